// Round 1
// baseline (2809.068 us; speedup 1.0000x reference)
//
#include <hip/hip_runtime.h>
#include <hip/hip_bf16.h>

#define IN_F   256
#define HID    64
#define HEADS  8
#define OUTC   40
#define ALPHA_SLOPE 0.2f
#define F1     (HEADS*HID)   // 512

// ---------------- CSR build ----------------

__global__ void hist_kernel(const int* __restrict__ col, int* __restrict__ cnt,
                            int E, int N) {
    int k = blockIdx.x * 256 + threadIdx.x;
    int tot = E + N;
    if (k >= tot) return;
    int c = (k < E) ? col[k] : (k - E);
    atomicAdd(&cnt[c], 1);
}

__global__ void scan_kernel(const int* __restrict__ cnt, int* __restrict__ indptr,
                            int* __restrict__ fill, int N) {
    __shared__ int sdata[1024];
    __shared__ int scarry;
    int tid = threadIdx.x;
    if (tid == 0) scarry = 0;
    __syncthreads();
    int ntiles = (N + 1023) >> 10;
    for (int t = 0; t < ntiles; t++) {
        int i = t * 1024 + tid;
        int v = (i < N) ? cnt[i] : 0;
        sdata[tid] = v;
        __syncthreads();
        for (int off = 1; off < 1024; off <<= 1) {
            int tv = (tid >= off) ? sdata[tid - off] : 0;
            __syncthreads();
            sdata[tid] += tv;
            __syncthreads();
        }
        int incl = sdata[tid];
        int carry = scarry;
        if (i < N) {
            int excl = carry + incl - v;
            indptr[i] = excl;
            fill[i] = excl;
        }
        __syncthreads();
        if (tid == 0) scarry = carry + sdata[1023];
        __syncthreads();
    }
    if (tid == 0) indptr[N] = scarry;
}

__global__ void scatter_kernel(const int* __restrict__ row, const int* __restrict__ col,
                               int* __restrict__ fill, int* __restrict__ csr,
                               int E, int N) {
    int k = blockIdx.x * 256 + threadIdx.x;
    int tot = E + N;
    if (k >= tot) return;
    int c = (k < E) ? col[k] : (k - E);
    int r = (k < E) ? row[k] : (k - E);
    int pos = atomicAdd(&fill[c], 1);
    csr[pos] = r;
}

// ---------------- fp32 tiled GEMM ----------------
// C[M, Ncols] = A[M, K] @ B, where B element (k, n) with n = ntile*64 + nl is at
// B[ntile*btile_stride + k*ldb + nl].  (heads: btile_stride=K*64, ldb=64; plain: 0, Ncols)

__global__ __launch_bounds__(256) void gemm_tile(
    const float* __restrict__ A, const float* __restrict__ B, float* __restrict__ C,
    int M, int K, int Ncols, long btile_stride, int ldb) {
    __shared__ float As[16][68];
    __shared__ float Bs[16][68];
    int tid = threadIdx.x;
    int m0 = blockIdx.x * 64;
    int n0 = blockIdx.y * 64;
    const float* Bb = B + (long)blockIdx.y * btile_stride;

    int tx = tid & 15;   // n micro
    int ty = tid >> 4;   // m micro
    int arow = tid >> 2; // 0..63
    int akv  = tid & 3;  // 0..3
    int bk   = tid >> 4; // 0..15
    int bnl  = (tid & 15) * 4;

    float acc[4][4];
    #pragma unroll
    for (int i = 0; i < 4; i++)
        #pragma unroll
        for (int j = 0; j < 4; j++) acc[i][j] = 0.f;

    for (int k0 = 0; k0 < K; k0 += 16) {
        float4 av = make_float4(0.f, 0.f, 0.f, 0.f);
        int am = m0 + arow;
        if (am < M) av = *(const float4*)(A + (long)am * K + k0 + akv * 4);
        float4 bv;
        if (n0 + bnl + 3 < Ncols) {
            bv = *(const float4*)(Bb + (long)(k0 + bk) * ldb + bnl);
        } else {
            const float* br = Bb + (long)(k0 + bk) * ldb;
            bv.x = (n0 + bnl + 0 < Ncols) ? br[bnl + 0] : 0.f;
            bv.y = (n0 + bnl + 1 < Ncols) ? br[bnl + 1] : 0.f;
            bv.z = (n0 + bnl + 2 < Ncols) ? br[bnl + 2] : 0.f;
            bv.w = (n0 + bnl + 3 < Ncols) ? br[bnl + 3] : 0.f;
        }
        __syncthreads();
        As[akv * 4 + 0][arow] = av.x;
        As[akv * 4 + 1][arow] = av.y;
        As[akv * 4 + 2][arow] = av.z;
        As[akv * 4 + 3][arow] = av.w;
        *(float4*)&Bs[bk][bnl] = bv;
        __syncthreads();
        #pragma unroll
        for (int k = 0; k < 16; k++) {
            float4 a = *(const float4*)&As[k][ty * 4];
            float4 b = *(const float4*)&Bs[k][tx * 4];
            acc[0][0] += a.x * b.x; acc[0][1] += a.x * b.y; acc[0][2] += a.x * b.z; acc[0][3] += a.x * b.w;
            acc[1][0] += a.y * b.x; acc[1][1] += a.y * b.y; acc[1][2] += a.y * b.z; acc[1][3] += a.y * b.w;
            acc[2][0] += a.z * b.x; acc[2][1] += a.z * b.y; acc[2][2] += a.z * b.z; acc[2][3] += a.z * b.w;
            acc[3][0] += a.w * b.x; acc[3][1] += a.w * b.y; acc[3][2] += a.w * b.z; acc[3][3] += a.w * b.w;
        }
    }
    #pragma unroll
    for (int i = 0; i < 4; i++) {
        int m = m0 + ty * 4 + i;
        if (m >= M) continue;
        #pragma unroll
        for (int j = 0; j < 4; j++) {
            int n = n0 + tx * 4 + j;
            if (n < Ncols) C[(long)m * Ncols + n] = acc[i][j];
        }
    }
}

// ---------------- attention scores ----------------
// 8-head layers: s_src[n,h] = Wh[n, h*64:h*64+64] . a[h, 0:64]; s_dst with a[h,64:128]

__global__ __launch_bounds__(256) void scores8_kernel(
    const float* __restrict__ Wh, const float* __restrict__ a,
    float* __restrict__ ssrc, float* __restrict__ sdst, int N) {
    int wid = blockIdx.x * 4 + (threadIdx.x >> 6);
    if (wid >= N * HEADS) return;
    int node = wid >> 3, head = wid & 7, lane = threadIdx.x & 63;
    float w = Wh[(long)node * F1 + head * HID + lane];
    float ss = w * a[head * 2 * HID + lane];
    float sd = w * a[head * 2 * HID + HID + lane];
    #pragma unroll
    for (int o = 32; o; o >>= 1) {
        ss += __shfl_xor(ss, o);
        sd += __shfl_xor(sd, o);
    }
    if (lane == 0) {
        ssrc[node * HEADS + head] = ss;
        sdst[node * HEADS + head] = sd;
    }
}

// out layer: F_out = 40, single head
__global__ __launch_bounds__(256) void scores1_kernel(
    const float* __restrict__ Wh, const float* __restrict__ a,
    float* __restrict__ ssrc, float* __restrict__ sdst, int N) {
    int node = blockIdx.x * 4 + (threadIdx.x >> 6);
    if (node >= N) return;
    int lane = threadIdx.x & 63;
    float w = (lane < OUTC) ? Wh[(long)node * OUTC + lane] : 0.f;
    float ss = (lane < OUTC) ? w * a[lane] : 0.f;
    float sd = (lane < OUTC) ? w * a[OUTC + lane] : 0.f;
    #pragma unroll
    for (int o = 32; o; o >>= 1) {
        ss += __shfl_xor(ss, o);
        sd += __shfl_xor(sd, o);
    }
    if (lane == 0) {
        ssrc[node] = ss;
        sdst[node] = sd;
    }
}

// ---------------- aggregation (gather over CSR, fused softmax + ELU) ----------------

__global__ __launch_bounds__(256) void agg8_kernel(
    const float* __restrict__ Wh, const float* __restrict__ ssrc,
    const float* __restrict__ sdst, const int* __restrict__ csr,
    const int* __restrict__ indptr, float* __restrict__ H, int N) {
    int wid = blockIdx.x * 4 + (threadIdx.x >> 6);
    if (wid >= N * HEADS) return;
    int node = wid >> 3, head = wid & 7, lane = threadIdx.x & 63;
    int s = indptr[node], e = indptr[node + 1];
    float sd = sdst[node * HEADS + head];
    float m = -1e30f;
    for (int j = s; j < e; j++) {
        int src = csr[j];
        float x = ssrc[src * HEADS + head] + sd;
        x = x > 0.f ? x : ALPHA_SLOPE * x;
        m = fmaxf(m, x);
    }
    float denom = 0.f, acc = 0.f;
    for (int j = s; j < e; j++) {
        int src = csr[j];
        float x = ssrc[src * HEADS + head] + sd;
        x = x > 0.f ? x : ALPHA_SLOPE * x;
        float w = __expf(x - m);
        denom += w;
        acc += w * Wh[(long)src * F1 + head * HID + lane];
    }
    float v = acc / denom;
    v = v > 0.f ? v : (__expf(v) - 1.f);   // ELU (concat layer)
    H[(long)node * F1 + head * HID + lane] = v;
}

// out layer: aggregate [N,40], then h = elu(out), then log_softmax over 40 classes
__global__ __launch_bounds__(256) void aggout_kernel(
    const float* __restrict__ Wh, const float* __restrict__ ssrc,
    const float* __restrict__ sdst, const int* __restrict__ csr,
    const int* __restrict__ indptr, float* __restrict__ out, int N) {
    int node = blockIdx.x * 4 + (threadIdx.x >> 6);
    if (node >= N) return;
    int lane = threadIdx.x & 63;
    int s = indptr[node], e = indptr[node + 1];
    float sd = sdst[node];
    float m = -1e30f;
    for (int j = s; j < e; j++) {
        int src = csr[j];
        float x = ssrc[src] + sd;
        x = x > 0.f ? x : ALPHA_SLOPE * x;
        m = fmaxf(m, x);
    }
    float denom = 0.f, acc = 0.f;
    for (int j = s; j < e; j++) {
        int src = csr[j];
        float x = ssrc[src] + sd;
        x = x > 0.f ? x : ALPHA_SLOPE * x;
        float w = __expf(x - m);
        denom += w;
        if (lane < OUTC) acc += w * Wh[(long)src * OUTC + lane];
    }
    float g = acc / denom;              // no ELU inside (concat=False)
    float v = g > 0.f ? g : (__expf(g) - 1.f);  // outer elu
    // log_softmax across 40 lanes
    float vm = (lane < OUTC) ? v : -1e30f;
    #pragma unroll
    for (int o = 32; o; o >>= 1) vm = fmaxf(vm, __shfl_xor(vm, o));
    float ex = (lane < OUTC) ? __expf(v - vm) : 0.f;
    #pragma unroll
    for (int o = 32; o; o >>= 1) ex += __shfl_xor(ex, o);
    if (lane < OUTC) out[(long)node * OUTC + lane] = v - vm - logf(ex);
}

// ---------------- launch ----------------

extern "C" void kernel_launch(void* const* d_in, const int* in_sizes, int n_in,
                              void* d_out, int out_size, void* d_ws, size_t ws_size,
                              hipStream_t stream) {
    const float* x    = (const float*)d_in[0];
    const int*   ei   = (const int*)d_in[1];
    const float* W0   = (const float*)d_in[2];
    const float* a0   = (const float*)d_in[3];
    const float* W1   = (const float*)d_in[4];
    const float* a1   = (const float*)d_in[5];
    const float* Wout = (const float*)d_in[6];
    const float* aout = (const float*)d_in[7];
    float* out = (float*)d_out;

    const int N = in_sizes[0] / IN_F;
    const int E = in_sizes[1] / 2;
    const int Etot = E + N;
    const int* erow = ei;
    const int* ecol = ei + E;

    // workspace carve
    char* p = (char*)d_ws;
    auto carve = [&](size_t bytes) {
        void* r = (void*)p;
        p += (bytes + 255) & ~(size_t)255;
        return r;
    };
    float* Wh     = (float*)carve((size_t)N * F1 * 4);  // also holds Whout [N,40]
    float* H      = (float*)carve((size_t)N * F1 * 4);
    float* ssrc   = (float*)carve((size_t)N * HEADS * 4);
    float* sdst   = (float*)carve((size_t)N * HEADS * 4);
    int*   cnt    = (int*)carve((size_t)N * 4);
    int*   indptr = (int*)carve((size_t)(N + 1) * 4);
    int*   fill   = (int*)carve((size_t)N * 4);
    int*   csr    = (int*)carve((size_t)Etot * 4);

    // CSR build (reused by all three layers)
    hipMemsetAsync(cnt, 0, (size_t)N * 4, stream);
    int eb = (Etot + 255) / 256;
    hist_kernel<<<eb, 256, 0, stream>>>(ecol, cnt, E, N);
    scan_kernel<<<1, 1024, 0, stream>>>(cnt, indptr, fill, N);
    scatter_kernel<<<eb, 256, 0, stream>>>(erow, ecol, fill, csr, E, N);

    int mtiles = (N + 63) / 64;
    int wb8 = (N * HEADS + 3) / 4;   // 4 waves / 256-thread block
    int wb1 = (N + 3) / 4;

    // Layer 0: x[N,256] @ W0 -> Wh[N,512]
    gemm_tile<<<dim3(mtiles, HEADS), 256, 0, stream>>>(x, W0, Wh, N, IN_F, F1,
                                                       (long)IN_F * HID, HID);
    scores8_kernel<<<wb8, 256, 0, stream>>>(Wh, a0, ssrc, sdst, N);
    agg8_kernel<<<wb8, 256, 0, stream>>>(Wh, ssrc, sdst, csr, indptr, H, N);

    // Layer 1: H[N,512] @ W1 -> Wh[N,512]
    gemm_tile<<<dim3(mtiles, HEADS), 256, 0, stream>>>(H, W1, Wh, N, F1, F1,
                                                       (long)F1 * HID, HID);
    scores8_kernel<<<wb8, 256, 0, stream>>>(Wh, a1, ssrc, sdst, N);
    agg8_kernel<<<wb8, 256, 0, stream>>>(Wh, ssrc, sdst, csr, indptr, H, N);

    // Out layer: H[N,512] @ Wout[512,40] -> Wh[N,40]
    gemm_tile<<<dim3(mtiles, 1), 256, 0, stream>>>(H, Wout, Wh, N, F1, OUTC, 0, OUTC);
    scores1_kernel<<<wb1, 256, 0, stream>>>(Wh, aout, ssrc, sdst, N);
    aggout_kernel<<<wb1, 256, 0, stream>>>(Wh, ssrc, sdst, csr, indptr, out, N);
}

// Round 2
// 1533.359 us; speedup vs baseline: 1.8320x; 1.8320x over previous
//
#include <hip/hip_runtime.h>
#include <hip/hip_bf16.h>

#define IN_F   256
#define HID    64
#define HEADS  8
#define OUTC   40
#define ALPHA_SLOPE 0.2f
#define F1     (HEADS*HID)   // 512

// ---------------- CSR build ----------------

__global__ void hist_kernel(const int* __restrict__ col, int* __restrict__ cnt,
                            int E, int N) {
    int k = blockIdx.x * 256 + threadIdx.x;
    int tot = E + N;
    if (k >= tot) return;
    int c = (k < E) ? col[k] : (k - E);
    atomicAdd(&cnt[c], 1);
}

__global__ void scan_kernel(const int* __restrict__ cnt, int* __restrict__ indptr,
                            int* __restrict__ fill, int N) {
    __shared__ int sdata[1024];
    __shared__ int scarry;
    int tid = threadIdx.x;
    if (tid == 0) scarry = 0;
    __syncthreads();
    int ntiles = (N + 1023) >> 10;
    for (int t = 0; t < ntiles; t++) {
        int i = t * 1024 + tid;
        int v = (i < N) ? cnt[i] : 0;
        sdata[tid] = v;
        __syncthreads();
        for (int off = 1; off < 1024; off <<= 1) {
            int tv = (tid >= off) ? sdata[tid - off] : 0;
            __syncthreads();
            sdata[tid] += tv;
            __syncthreads();
        }
        int incl = sdata[tid];
        int carry = scarry;
        if (i < N) {
            int excl = carry + incl - v;
            indptr[i] = excl;
            fill[i] = excl;
        }
        __syncthreads();
        if (tid == 0) scarry = carry + sdata[1023];
        __syncthreads();
    }
    if (tid == 0) indptr[N] = scarry;
}

__global__ void scatter_kernel(const int* __restrict__ row, const int* __restrict__ col,
                               int* __restrict__ fill, int* __restrict__ csr,
                               int E, int N) {
    int k = blockIdx.x * 256 + threadIdx.x;
    int tot = E + N;
    if (k >= tot) return;
    int c = (k < E) ? col[k] : (k - E);
    int r = (k < E) ? row[k] : (k - E);
    int pos = atomicAdd(&fill[c], 1);
    csr[pos] = r;
}

// ---------------- fp32 tiled GEMM ----------------

__global__ __launch_bounds__(256) void gemm_tile(
    const float* __restrict__ A, const float* __restrict__ B, float* __restrict__ C,
    int M, int K, int Ncols, long btile_stride, int ldb) {
    __shared__ float As[16][68];
    __shared__ float Bs[16][68];
    int tid = threadIdx.x;
    int m0 = blockIdx.x * 64;
    int n0 = blockIdx.y * 64;
    const float* Bb = B + (long)blockIdx.y * btile_stride;

    int tx = tid & 15;
    int ty = tid >> 4;
    int arow = tid >> 2;
    int akv  = tid & 3;
    int bk   = tid >> 4;
    int bnl  = (tid & 15) * 4;

    float acc[4][4];
    #pragma unroll
    for (int i = 0; i < 4; i++)
        #pragma unroll
        for (int j = 0; j < 4; j++) acc[i][j] = 0.f;

    for (int k0 = 0; k0 < K; k0 += 16) {
        float4 av = make_float4(0.f, 0.f, 0.f, 0.f);
        int am = m0 + arow;
        if (am < M) av = *(const float4*)(A + (long)am * K + k0 + akv * 4);
        float4 bv;
        if (n0 + bnl + 3 < Ncols) {
            bv = *(const float4*)(Bb + (long)(k0 + bk) * ldb + bnl);
        } else {
            const float* br = Bb + (long)(k0 + bk) * ldb;
            bv.x = (n0 + bnl + 0 < Ncols) ? br[bnl + 0] : 0.f;
            bv.y = (n0 + bnl + 1 < Ncols) ? br[bnl + 1] : 0.f;
            bv.z = (n0 + bnl + 2 < Ncols) ? br[bnl + 2] : 0.f;
            bv.w = (n0 + bnl + 3 < Ncols) ? br[bnl + 3] : 0.f;
        }
        __syncthreads();
        As[akv * 4 + 0][arow] = av.x;
        As[akv * 4 + 1][arow] = av.y;
        As[akv * 4 + 2][arow] = av.z;
        As[akv * 4 + 3][arow] = av.w;
        *(float4*)&Bs[bk][bnl] = bv;
        __syncthreads();
        #pragma unroll
        for (int k = 0; k < 16; k++) {
            float4 a = *(const float4*)&As[k][ty * 4];
            float4 b = *(const float4*)&Bs[k][tx * 4];
            acc[0][0] += a.x * b.x; acc[0][1] += a.x * b.y; acc[0][2] += a.x * b.z; acc[0][3] += a.x * b.w;
            acc[1][0] += a.y * b.x; acc[1][1] += a.y * b.y; acc[1][2] += a.y * b.z; acc[1][3] += a.y * b.w;
            acc[2][0] += a.z * b.x; acc[2][1] += a.z * b.y; acc[2][2] += a.z * b.z; acc[2][3] += a.z * b.w;
            acc[3][0] += a.w * b.x; acc[3][1] += a.w * b.y; acc[3][2] += a.w * b.z; acc[3][3] += a.w * b.w;
        }
    }
    #pragma unroll
    for (int i = 0; i < 4; i++) {
        int m = m0 + ty * 4 + i;
        if (m >= M) continue;
        #pragma unroll
        for (int j = 0; j < 4; j++) {
            int n = n0 + tx * 4 + j;
            if (n < Ncols) C[(long)m * Ncols + n] = acc[i][j];
        }
    }
}

// ---------------- attention scores ----------------

__global__ __launch_bounds__(256) void scores8_kernel(
    const float* __restrict__ Wh, const float* __restrict__ a,
    float* __restrict__ ssrc, float* __restrict__ sdst, int N) {
    int wid = blockIdx.x * 4 + (threadIdx.x >> 6);
    if (wid >= N * HEADS) return;
    int node = wid >> 3, head = wid & 7, lane = threadIdx.x & 63;
    float w = Wh[(long)node * F1 + head * HID + lane];
    float ss = w * a[head * 2 * HID + lane];
    float sd = w * a[head * 2 * HID + HID + lane];
    #pragma unroll
    for (int o = 32; o; o >>= 1) {
        ss += __shfl_xor(ss, o);
        sd += __shfl_xor(sd, o);
    }
    if (lane == 0) {
        ssrc[node * HEADS + head] = ss;
        sdst[node * HEADS + head] = sd;
    }
}

__global__ __launch_bounds__(256) void scores1_kernel(
    const float* __restrict__ Wh, const float* __restrict__ a,
    float* __restrict__ ssrc, float* __restrict__ sdst, int N) {
    int node = blockIdx.x * 4 + (threadIdx.x >> 6);
    if (node >= N) return;
    int lane = threadIdx.x & 63;
    float w = (lane < OUTC) ? Wh[(long)node * OUTC + lane] : 0.f;
    float ss = (lane < OUTC) ? w * a[lane] : 0.f;
    float sd = (lane < OUTC) ? w * a[OUTC + lane] : 0.f;
    #pragma unroll
    for (int o = 32; o; o >>= 1) {
        ss += __shfl_xor(ss, o);
        sd += __shfl_xor(sd, o);
    }
    if (lane == 0) {
        ssrc[node] = ss;
        sdst[node] = sd;
    }
}

// ---------------- aggregation: edge-dim parallelized across lanes ----------------
// Per (node,head) wave. Phase 1 (per 64-edge tile): lanes cooperatively load
// csr + gather ssrc (64 loads in flight), shuffle-reduce max/denom with
// online-softmax rescale across tiles. Phase 2: broadcast loop, loads
// independent across j — only the 4-cycle FMA chain is serial.

__global__ __launch_bounds__(256) void agg8_kernel(
    const float* __restrict__ Wh, const float* __restrict__ ssrc,
    const float* __restrict__ sdst, const int* __restrict__ csr,
    const int* __restrict__ indptr, float* __restrict__ H, int N) {
    int wid = blockIdx.x * 4 + (threadIdx.x >> 6);
    if (wid >= N * HEADS) return;
    int node = wid >> 3, head = wid & 7, lane = threadIdx.x & 63;
    int s = __builtin_amdgcn_readfirstlane(indptr[node]);
    int e = __builtin_amdgcn_readfirstlane(indptr[node + 1]);
    float sd = sdst[node * HEADS + head];
    const float* whb = Wh + head * HID + lane;

    float m_run = -1e30f, d_run = 0.f, acc = 0.f;
    for (int t = s; t < e; t += 64) {
        int cnt = min(64, e - t);
        int src_i = node;
        float x_i = -1e30f;
        if (lane < cnt) {
            src_i = csr[t + lane];
            float x = ssrc[src_i * HEADS + head] + sd;
            x_i = x > 0.f ? x : ALPHA_SLOPE * x;
        }
        float tm = x_i;
        #pragma unroll
        for (int o = 32; o; o >>= 1) tm = fmaxf(tm, __shfl_xor(tm, o));
        float nm = fmaxf(m_run, tm);
        float scale = __expf(m_run - nm);
        acc *= scale; d_run *= scale;
        m_run = nm;
        float w_i = __expf(x_i - nm);     // 0 for invalid lanes
        float ts = w_i;
        #pragma unroll
        for (int o = 32; o; o >>= 1) ts += __shfl_xor(ts, o);
        d_run += ts;
        int cnt4 = (cnt + 3) & ~3;        // pad lanes have w=0, src=node (safe)
        for (int j = 0; j < cnt4; j += 4) {
            #pragma unroll
            for (int u = 0; u < 4; u++) {
                int   sj = __shfl(src_i, j + u);
                float wj = __shfl(w_i,  j + u);
                acc += wj * whb[(long)sj * F1];
            }
        }
    }
    float v = acc / d_run;
    v = v > 0.f ? v : (__expf(v) - 1.f);   // ELU (concat layer)
    H[(long)node * F1 + head * HID + lane] = v;
}

__global__ __launch_bounds__(256) void aggout_kernel(
    const float* __restrict__ Wh, const float* __restrict__ ssrc,
    const float* __restrict__ sdst, const int* __restrict__ csr,
    const int* __restrict__ indptr, float* __restrict__ out, int N) {
    int node = blockIdx.x * 4 + (threadIdx.x >> 6);
    if (node >= N) return;
    int lane = threadIdx.x & 63;
    int s = __builtin_amdgcn_readfirstlane(indptr[node]);
    int e = __builtin_amdgcn_readfirstlane(indptr[node + 1]);
    float sd = sdst[node];
    int lc = min(lane, OUTC - 1);          // clamped class index for loads
    const float* whb = Wh + lc;

    float m_run = -1e30f, d_run = 0.f, acc = 0.f;
    for (int t = s; t < e; t += 64) {
        int cnt = min(64, e - t);
        int src_i = node;
        float x_i = -1e30f;
        if (lane < cnt) {
            src_i = csr[t + lane];
            float x = ssrc[src_i] + sd;
            x_i = x > 0.f ? x : ALPHA_SLOPE * x;
        }
        float tm = x_i;
        #pragma unroll
        for (int o = 32; o; o >>= 1) tm = fmaxf(tm, __shfl_xor(tm, o));
        float nm = fmaxf(m_run, tm);
        float scale = __expf(m_run - nm);
        acc *= scale; d_run *= scale;
        m_run = nm;
        float w_i = __expf(x_i - nm);
        float ts = w_i;
        #pragma unroll
        for (int o = 32; o; o >>= 1) ts += __shfl_xor(ts, o);
        d_run += ts;
        int cnt4 = (cnt + 3) & ~3;
        for (int j = 0; j < cnt4; j += 4) {
            #pragma unroll
            for (int u = 0; u < 4; u++) {
                int   sj = __shfl(src_i, j + u);
                float wj = __shfl(w_i,  j + u);
                acc += wj * whb[(long)sj * OUTC];
            }
        }
    }
    float g = acc / d_run;
    float v = g > 0.f ? g : (__expf(g) - 1.f);   // outer elu
    float vm = (lane < OUTC) ? v : -1e30f;
    #pragma unroll
    for (int o = 32; o; o >>= 1) vm = fmaxf(vm, __shfl_xor(vm, o));
    float ex = (lane < OUTC) ? __expf(v - vm) : 0.f;
    #pragma unroll
    for (int o = 32; o; o >>= 1) ex += __shfl_xor(ex, o);
    if (lane < OUTC) out[(long)node * OUTC + lane] = v - vm - logf(ex);
}

// ---------------- launch ----------------

extern "C" void kernel_launch(void* const* d_in, const int* in_sizes, int n_in,
                              void* d_out, int out_size, void* d_ws, size_t ws_size,
                              hipStream_t stream) {
    const float* x    = (const float*)d_in[0];
    const int*   ei   = (const int*)d_in[1];
    const float* W0   = (const float*)d_in[2];
    const float* a0   = (const float*)d_in[3];
    const float* W1   = (const float*)d_in[4];
    const float* a1   = (const float*)d_in[5];
    const float* Wout = (const float*)d_in[6];
    const float* aout = (const float*)d_in[7];
    float* out = (float*)d_out;

    const int N = in_sizes[0] / IN_F;
    const int E = in_sizes[1] / 2;
    const int Etot = E + N;
    const int* erow = ei;
    const int* ecol = ei + E;

    char* p = (char*)d_ws;
    auto carve = [&](size_t bytes) {
        void* r = (void*)p;
        p += (bytes + 255) & ~(size_t)255;
        return r;
    };
    float* Wh     = (float*)carve((size_t)N * F1 * 4);
    float* H      = (float*)carve((size_t)N * F1 * 4);
    float* ssrc   = (float*)carve((size_t)N * HEADS * 4);
    float* sdst   = (float*)carve((size_t)N * HEADS * 4);
    int*   cnt    = (int*)carve((size_t)N * 4);
    int*   indptr = (int*)carve((size_t)(N + 1) * 4);
    int*   fill   = (int*)carve((size_t)N * 4);
    int*   csr    = (int*)carve((size_t)Etot * 4);

    hipMemsetAsync(cnt, 0, (size_t)N * 4, stream);
    int eb = (Etot + 255) / 256;
    hist_kernel<<<eb, 256, 0, stream>>>(ecol, cnt, E, N);
    scan_kernel<<<1, 1024, 0, stream>>>(cnt, indptr, fill, N);
    scatter_kernel<<<eb, 256, 0, stream>>>(erow, ecol, fill, csr, E, N);

    int mtiles = (N + 63) / 64;
    int wb8 = (N * HEADS + 3) / 4;
    int wb1 = (N + 3) / 4;

    gemm_tile<<<dim3(mtiles, HEADS), 256, 0, stream>>>(x, W0, Wh, N, IN_F, F1,
                                                       (long)IN_F * HID, HID);
    scores8_kernel<<<wb8, 256, 0, stream>>>(Wh, a0, ssrc, sdst, N);
    agg8_kernel<<<wb8, 256, 0, stream>>>(Wh, ssrc, sdst, csr, indptr, H, N);

    gemm_tile<<<dim3(mtiles, HEADS), 256, 0, stream>>>(H, W1, Wh, N, F1, F1,
                                                       (long)F1 * HID, HID);
    scores8_kernel<<<wb8, 256, 0, stream>>>(Wh, a1, ssrc, sdst, N);
    agg8_kernel<<<wb8, 256, 0, stream>>>(Wh, ssrc, sdst, csr, indptr, H, N);

    gemm_tile<<<dim3(mtiles, 1), 256, 0, stream>>>(H, Wout, Wh, N, F1, OUTC, 0, OUTC);
    scores1_kernel<<<wb1, 256, 0, stream>>>(Wh, aout, ssrc, sdst, N);
    aggout_kernel<<<wb1, 256, 0, stream>>>(Wh, ssrc, sdst, csr, indptr, out, N);
}

// Round 3
// 1100.206 us; speedup vs baseline: 2.5532x; 1.3937x over previous
//
#include <hip/hip_runtime.h>
#include <hip/hip_bf16.h>

#define IN_F   256
#define HID    64
#define HEADS  8
#define OUTC   40
#define ALPHA_SLOPE 0.2f
#define F1     (HEADS*HID)   // 512

typedef short bf16x8 __attribute__((ext_vector_type(8)));
typedef float f32x4  __attribute__((ext_vector_type(4)));

// ---------------- CSR build ----------------

__global__ void hist_kernel(const int* __restrict__ col, int* __restrict__ cnt,
                            int E, int N) {
    int k = blockIdx.x * 256 + threadIdx.x;
    int tot = E + N;
    if (k >= tot) return;
    int c = (k < E) ? col[k] : (k - E);
    atomicAdd(&cnt[c], 1);
}

__global__ void scan_kernel(const int* __restrict__ cnt, int* __restrict__ indptr,
                            int* __restrict__ fill, int N) {
    __shared__ int sdata[1024];
    __shared__ int scarry;
    int tid = threadIdx.x;
    if (tid == 0) scarry = 0;
    __syncthreads();
    int ntiles = (N + 1023) >> 10;
    for (int t = 0; t < ntiles; t++) {
        int i = t * 1024 + tid;
        int v = (i < N) ? cnt[i] : 0;
        sdata[tid] = v;
        __syncthreads();
        for (int off = 1; off < 1024; off <<= 1) {
            int tv = (tid >= off) ? sdata[tid - off] : 0;
            __syncthreads();
            sdata[tid] += tv;
            __syncthreads();
        }
        int incl = sdata[tid];
        int carry = scarry;
        if (i < N) {
            int excl = carry + incl - v;
            indptr[i] = excl;
            fill[i] = excl;
        }
        __syncthreads();
        if (tid == 0) scarry = carry + sdata[1023];
        __syncthreads();
    }
    if (tid == 0) indptr[N] = scarry;
}

__global__ void scatter_kernel(const int* __restrict__ row, const int* __restrict__ col,
                               int* __restrict__ fill, int* __restrict__ csr,
                               int E, int N) {
    int k = blockIdx.x * 256 + threadIdx.x;
    int tot = E + N;
    if (k >= tot) return;
    int c = (k < E) ? col[k] : (k - E);
    int r = (k < E) ? row[k] : (k - E);
    int pos = atomicAdd(&fill[c], 1);
    csr[pos] = r;
}

// ---------------- prep: fp32 -> bf16 converts / weight transposes ----------------

__global__ void cvt_bf16_kernel(const float* __restrict__ in,
                                __hip_bfloat16* __restrict__ out, long n) {
    long i = ((long)blockIdx.x * 256 + threadIdx.x) * 4;
    if (i + 3 >= n) {
        for (long j = i; j < n; j++) out[j] = __float2bfloat16(in[j]);
        return;
    }
    float4 v = *(const float4*)(in + i);
    out[i + 0] = __float2bfloat16(v.x);
    out[i + 1] = __float2bfloat16(v.y);
    out[i + 2] = __float2bfloat16(v.z);
    out[i + 3] = __float2bfloat16(v.w);
}

// W [8][K][64] -> Wt [8][64][K] bf16
__global__ void prep_w8_kernel(const float* __restrict__ W,
                               __hip_bfloat16* __restrict__ Wt, int K) {
    long i = (long)blockIdx.x * 256 + threadIdx.x;
    long tot = (long)HEADS * K * 64;
    if (i >= tot) return;
    int n = i & 63;
    long rest = i >> 6;
    int k = (int)(rest % K);
    int h = (int)(rest / K);
    Wt[((long)h * 64 + n) * K + k] = __float2bfloat16(W[i]);
}

// Wout [512][40] -> Wt [64][512] bf16, rows 40..63 zero
__global__ void prep_wout_kernel(const float* __restrict__ W,
                                 __hip_bfloat16* __restrict__ Wt) {
    int i = blockIdx.x * 256 + threadIdx.x;
    if (i >= 64 * 512) return;
    int k = i & 511;
    int n = i >> 9;
    Wt[i] = __float2bfloat16(n < OUTC ? W[(long)k * OUTC + n] : 0.f);
}

// ---------------- bf16 MFMA GEMM ----------------
// C[M, NcolsTot] tile (128 x 64) per block; blockIdx.y = column/head tile.
// A bf16 [M][K] row-major. Bt bf16 [ytiles][64][K] (B transposed per tile).
// MFMA 16x16x32: A frag A[m=lane&15][k=(lane>>4)*8+j]; B frag B[k][n=lane&15];
// C/D: col=lane&15, row=(lane>>4)*4+reg.

__global__ __launch_bounds__(256) void gemm_mfma(
    const __hip_bfloat16* __restrict__ A, const __hip_bfloat16* __restrict__ Bt,
    float* __restrict__ C, int M, int K, int NcolsTot) {
    constexpr int LDA = 40;                 // pad 32->40: 2-way bank max (free)
    __shared__ __hip_bfloat16 As[128 * LDA];
    __shared__ __hip_bfloat16 Bs[64 * LDA];
    int tid = threadIdx.x;
    int m0 = blockIdx.x * 128;
    const __hip_bfloat16* Bth = Bt + (long)blockIdx.y * 64 * K;
    int col0 = blockIdx.y * 64;
    int lane = tid & 63, wave = tid >> 6;
    int wm = wave * 32;
    int arow = tid >> 2, acol = (tid & 3) * 8;
    int fr = lane & 15, fq = lane >> 4;

    f32x4 acc[2][4] = {};

    for (int k0 = 0; k0 < K; k0 += 32) {
        int ma = min(m0 + arow, M - 1);
        int mb = min(m0 + 64 + arow, M - 1);
        float4 av1 = *(const float4*)(A + (long)ma * K + k0 + acol);
        float4 av2 = *(const float4*)(A + (long)mb * K + k0 + acol);
        float4 bv  = *(const float4*)(Bth + (long)arow * K + k0 + acol);
        __syncthreads();
        *(float4*)(As + arow * LDA + acol) = av1;
        *(float4*)(As + (64 + arow) * LDA + acol) = av2;
        *(float4*)(Bs + arow * LDA + acol) = bv;
        __syncthreads();
        bf16x8 a0 = *(const bf16x8*)(As + (wm + fr) * LDA + fq * 8);
        bf16x8 a1 = *(const bf16x8*)(As + (wm + 16 + fr) * LDA + fq * 8);
        #pragma unroll
        for (int ni = 0; ni < 4; ni++) {
            bf16x8 b = *(const bf16x8*)(Bs + (ni * 16 + fr) * LDA + fq * 8);
            acc[0][ni] = __builtin_amdgcn_mfma_f32_16x16x32_bf16(a0, b, acc[0][ni], 0, 0, 0);
            acc[1][ni] = __builtin_amdgcn_mfma_f32_16x16x32_bf16(a1, b, acc[1][ni], 0, 0, 0);
        }
    }

    #pragma unroll
    for (int mi = 0; mi < 2; mi++)
        #pragma unroll
        for (int ni = 0; ni < 4; ni++)
            #pragma unroll
            for (int rr = 0; rr < 4; rr++) {
                int m = m0 + wm + mi * 16 + fq * 4 + rr;
                int n = col0 + ni * 16 + fr;
                if (m < M && n < NcolsTot)
                    C[(long)m * NcolsTot + n] = acc[mi][ni][rr];
            }
}

// ---------------- attention scores ----------------

__global__ __launch_bounds__(256) void scores8_kernel(
    const float* __restrict__ Wh, const float* __restrict__ a,
    float* __restrict__ ssrc, float* __restrict__ sdst, int N) {
    int wid = blockIdx.x * 4 + (threadIdx.x >> 6);
    if (wid >= N * HEADS) return;
    int node = wid >> 3, head = wid & 7, lane = threadIdx.x & 63;
    float w = Wh[(long)node * F1 + head * HID + lane];
    float ss = w * a[head * 2 * HID + lane];
    float sd = w * a[head * 2 * HID + HID + lane];
    #pragma unroll
    for (int o = 32; o; o >>= 1) {
        ss += __shfl_xor(ss, o);
        sd += __shfl_xor(sd, o);
    }
    if (lane == 0) {
        ssrc[node * HEADS + head] = ss;
        sdst[node * HEADS + head] = sd;
    }
}

__global__ __launch_bounds__(256) void scores1_kernel(
    const float* __restrict__ Wh, const float* __restrict__ a,
    float* __restrict__ ssrc, float* __restrict__ sdst, int N) {
    int node = blockIdx.x * 4 + (threadIdx.x >> 6);
    if (node >= N) return;
    int lane = threadIdx.x & 63;
    float w = (lane < OUTC) ? Wh[(long)node * OUTC + lane] : 0.f;
    float ss = (lane < OUTC) ? w * a[lane] : 0.f;
    float sd = (lane < OUTC) ? w * a[OUTC + lane] : 0.f;
    #pragma unroll
    for (int o = 32; o; o >>= 1) {
        ss += __shfl_xor(ss, o);
        sd += __shfl_xor(sd, o);
    }
    if (lane == 0) {
        ssrc[node] = ss;
        sdst[node] = sd;
    }
}

// ---------------- aggregation (edge-dim parallel, online softmax) ----------------

__global__ __launch_bounds__(256) void agg8_kernel(
    const float* __restrict__ Wh, const float* __restrict__ ssrc,
    const float* __restrict__ sdst, const int* __restrict__ csr,
    const int* __restrict__ indptr, __hip_bfloat16* __restrict__ H, int N) {
    int wid = blockIdx.x * 4 + (threadIdx.x >> 6);
    if (wid >= N * HEADS) return;
    int node = wid >> 3, head = wid & 7, lane = threadIdx.x & 63;
    int s = __builtin_amdgcn_readfirstlane(indptr[node]);
    int e = __builtin_amdgcn_readfirstlane(indptr[node + 1]);
    float sd = sdst[node * HEADS + head];
    const float* whb = Wh + head * HID + lane;

    float m_run = -1e30f, d_run = 0.f, acc = 0.f;
    for (int t = s; t < e; t += 64) {
        int cnt = min(64, e - t);
        int src_i = node;
        float x_i = -1e30f;
        if (lane < cnt) {
            src_i = csr[t + lane];
            float x = ssrc[src_i * HEADS + head] + sd;
            x_i = x > 0.f ? x : ALPHA_SLOPE * x;
        }
        float tm = x_i;
        #pragma unroll
        for (int o = 32; o; o >>= 1) tm = fmaxf(tm, __shfl_xor(tm, o));
        float nm = fmaxf(m_run, tm);
        float scale = __expf(m_run - nm);
        acc *= scale; d_run *= scale;
        m_run = nm;
        float w_i = __expf(x_i - nm);
        float ts = w_i;
        #pragma unroll
        for (int o = 32; o; o >>= 1) ts += __shfl_xor(ts, o);
        d_run += ts;
        int cnt4 = (cnt + 3) & ~3;
        for (int j = 0; j < cnt4; j += 4) {
            #pragma unroll
            for (int u = 0; u < 4; u++) {
                int   sj = __shfl(src_i, j + u);
                float wj = __shfl(w_i,  j + u);
                acc += wj * whb[(long)sj * F1];
            }
        }
    }
    float v = acc / d_run;
    v = v > 0.f ? v : (__expf(v) - 1.f);   // ELU (concat layer)
    H[(long)node * F1 + head * HID + lane] = __float2bfloat16(v);
}

__global__ __launch_bounds__(256) void aggout_kernel(
    const float* __restrict__ Wh, const float* __restrict__ ssrc,
    const float* __restrict__ sdst, const int* __restrict__ csr,
    const int* __restrict__ indptr, float* __restrict__ out, int N) {
    int node = blockIdx.x * 4 + (threadIdx.x >> 6);
    if (node >= N) return;
    int lane = threadIdx.x & 63;
    int s = __builtin_amdgcn_readfirstlane(indptr[node]);
    int e = __builtin_amdgcn_readfirstlane(indptr[node + 1]);
    float sd = sdst[node];
    int lc = min(lane, OUTC - 1);
    const float* whb = Wh + lc;

    float m_run = -1e30f, d_run = 0.f, acc = 0.f;
    for (int t = s; t < e; t += 64) {
        int cnt = min(64, e - t);
        int src_i = node;
        float x_i = -1e30f;
        if (lane < cnt) {
            src_i = csr[t + lane];
            float x = ssrc[src_i] + sd;
            x_i = x > 0.f ? x : ALPHA_SLOPE * x;
        }
        float tm = x_i;
        #pragma unroll
        for (int o = 32; o; o >>= 1) tm = fmaxf(tm, __shfl_xor(tm, o));
        float nm = fmaxf(m_run, tm);
        float scale = __expf(m_run - nm);
        acc *= scale; d_run *= scale;
        m_run = nm;
        float w_i = __expf(x_i - nm);
        float ts = w_i;
        #pragma unroll
        for (int o = 32; o; o >>= 1) ts += __shfl_xor(ts, o);
        d_run += ts;
        int cnt4 = (cnt + 3) & ~3;
        for (int j = 0; j < cnt4; j += 4) {
            #pragma unroll
            for (int u = 0; u < 4; u++) {
                int   sj = __shfl(src_i, j + u);
                float wj = __shfl(w_i,  j + u);
                acc += wj * whb[(long)sj * OUTC];
            }
        }
    }
    float g = acc / d_run;
    float v = g > 0.f ? g : (__expf(g) - 1.f);
    float vm = (lane < OUTC) ? v : -1e30f;
    #pragma unroll
    for (int o = 32; o; o >>= 1) vm = fmaxf(vm, __shfl_xor(vm, o));
    float ex = (lane < OUTC) ? __expf(v - vm) : 0.f;
    #pragma unroll
    for (int o = 32; o; o >>= 1) ex += __shfl_xor(ex, o);
    if (lane < OUTC) out[(long)node * OUTC + lane] = v - vm - logf(ex);
}

// ---------------- launch ----------------

extern "C" void kernel_launch(void* const* d_in, const int* in_sizes, int n_in,
                              void* d_out, int out_size, void* d_ws, size_t ws_size,
                              hipStream_t stream) {
    const float* x    = (const float*)d_in[0];
    const int*   ei   = (const int*)d_in[1];
    const float* W0   = (const float*)d_in[2];
    const float* a0   = (const float*)d_in[3];
    const float* W1   = (const float*)d_in[4];
    const float* a1   = (const float*)d_in[5];
    const float* Wout = (const float*)d_in[6];
    const float* aout = (const float*)d_in[7];
    float* out = (float*)d_out;

    const int N = in_sizes[0] / IN_F;
    const int E = in_sizes[1] / 2;
    const int Etot = E + N;
    const int* erow = ei;
    const int* ecol = ei + E;

    char* p = (char*)d_ws;
    auto carve = [&](size_t bytes) {
        void* r = (void*)p;
        p += (bytes + 255) & ~(size_t)255;
        return r;
    };
    float*           Wh   = (float*)carve((size_t)N * F1 * 4);       // fp32 GEMM out
    __hip_bfloat16*  Hb   = (__hip_bfloat16*)carve((size_t)N * F1 * 2);
    __hip_bfloat16*  xb   = (__hip_bfloat16*)carve((size_t)N * IN_F * 2);
    __hip_bfloat16*  Wt0  = (__hip_bfloat16*)carve((size_t)HEADS * 64 * IN_F * 2);
    __hip_bfloat16*  Wt1  = (__hip_bfloat16*)carve((size_t)HEADS * 64 * F1 * 2);
    __hip_bfloat16*  WtO  = (__hip_bfloat16*)carve((size_t)64 * F1 * 2);
    float*  ssrc   = (float*)carve((size_t)N * HEADS * 4);
    float*  sdst   = (float*)carve((size_t)N * HEADS * 4);
    int*    cnt    = (int*)carve((size_t)N * 4);
    int*    indptr = (int*)carve((size_t)(N + 1) * 4);
    int*    fill   = (int*)carve((size_t)N * 4);
    int*    csr    = (int*)carve((size_t)Etot * 4);

    // CSR build
    hipMemsetAsync(cnt, 0, (size_t)N * 4, stream);
    int eb = (Etot + 255) / 256;
    hist_kernel<<<eb, 256, 0, stream>>>(ecol, cnt, E, N);
    scan_kernel<<<1, 1024, 0, stream>>>(cnt, indptr, fill, N);
    scatter_kernel<<<eb, 256, 0, stream>>>(erow, ecol, fill, csr, E, N);

    // prep bf16 operands
    long nx = (long)N * IN_F;
    cvt_bf16_kernel<<<(int)((nx / 4 + 255) / 256), 256, 0, stream>>>(x, xb, nx);
    prep_w8_kernel<<<(HEADS * IN_F * 64 + 255) / 256, 256, 0, stream>>>(W0, Wt0, IN_F);
    prep_w8_kernel<<<(HEADS * F1 * 64 + 255) / 256, 256, 0, stream>>>(W1, Wt1, F1);
    prep_wout_kernel<<<(64 * 512 + 255) / 256, 256, 0, stream>>>(Wout, WtO);

    int mtiles = (N + 127) / 128;
    int wb8 = (N * HEADS + 3) / 4;
    int wb1 = (N + 3) / 4;

    // Layer 0
    gemm_mfma<<<dim3(mtiles, HEADS), 256, 0, stream>>>(xb, Wt0, Wh, N, IN_F, F1);
    scores8_kernel<<<wb8, 256, 0, stream>>>(Wh, a0, ssrc, sdst, N);
    agg8_kernel<<<wb8, 256, 0, stream>>>(Wh, ssrc, sdst, csr, indptr, Hb, N);

    // Layer 1
    gemm_mfma<<<dim3(mtiles, HEADS), 256, 0, stream>>>(Hb, Wt1, Wh, N, F1, F1);
    scores8_kernel<<<wb8, 256, 0, stream>>>(Wh, a1, ssrc, sdst, N);
    agg8_kernel<<<wb8, 256, 0, stream>>>(Wh, ssrc, sdst, csr, indptr, Hb, N);

    // Out layer
    gemm_mfma<<<dim3(mtiles, 1), 256, 0, stream>>>(Hb, WtO, Wh, N, F1, OUTC);
    scores1_kernel<<<wb1, 256, 0, stream>>>(Wh, aout, ssrc, sdst, N);
    aggout_kernel<<<wb1, 256, 0, stream>>>(Wh, ssrc, sdst, csr, indptr, out, N);
}

// Round 4
// 1047.146 us; speedup vs baseline: 2.6826x; 1.0507x over previous
//
#include <hip/hip_runtime.h>
#include <hip/hip_bf16.h>

#define IN_F   256
#define HID    64
#define HEADS  8
#define OUTC   40
#define ALPHA_SLOPE 0.2f
#define F1     (HEADS*HID)   // 512

typedef short bf16x8 __attribute__((ext_vector_type(8)));
typedef float f32x4  __attribute__((ext_vector_type(4)));

// ---------------- CSR build ----------------

__global__ void hist_kernel(const int* __restrict__ col, int* __restrict__ cnt,
                            int E, int N) {
    int k = blockIdx.x * 256 + threadIdx.x;
    int tot = E + N;
    if (k >= tot) return;
    int c = (k < E) ? col[k] : (k - E);
    atomicAdd(&cnt[c], 1);
}

__global__ void scan_kernel(const int* __restrict__ cnt, int* __restrict__ indptr,
                            int* __restrict__ fill, int N) {
    __shared__ int sdata[1024];
    __shared__ int scarry;
    int tid = threadIdx.x;
    if (tid == 0) scarry = 0;
    __syncthreads();
    int ntiles = (N + 1023) >> 10;
    for (int t = 0; t < ntiles; t++) {
        int i = t * 1024 + tid;
        int v = (i < N) ? cnt[i] : 0;
        sdata[tid] = v;
        __syncthreads();
        for (int off = 1; off < 1024; off <<= 1) {
            int tv = (tid >= off) ? sdata[tid - off] : 0;
            __syncthreads();
            sdata[tid] += tv;
            __syncthreads();
        }
        int incl = sdata[tid];
        int carry = scarry;
        if (i < N) {
            int excl = carry + incl - v;
            indptr[i] = excl;
            fill[i] = excl;
        }
        __syncthreads();
        if (tid == 0) scarry = carry + sdata[1023];
        __syncthreads();
    }
    if (tid == 0) indptr[N] = scarry;
}

__global__ void scatter_kernel(const int* __restrict__ row, const int* __restrict__ col,
                               int* __restrict__ fill, int* __restrict__ csr,
                               int E, int N) {
    int k = blockIdx.x * 256 + threadIdx.x;
    int tot = E + N;
    if (k >= tot) return;
    int c = (k < E) ? col[k] : (k - E);
    int r = (k < E) ? row[k] : (k - E);
    int pos = atomicAdd(&fill[c], 1);
    csr[pos] = r;
}

// ---------------- prep: fp32 -> bf16 converts / weight transposes ----------------

__global__ void cvt_bf16_kernel(const float* __restrict__ in,
                                __hip_bfloat16* __restrict__ out, long n) {
    long i = ((long)blockIdx.x * 256 + threadIdx.x) * 4;
    if (i + 3 >= n) {
        for (long j = i; j < n; j++) out[j] = __float2bfloat16(in[j]);
        return;
    }
    float4 v = *(const float4*)(in + i);
    out[i + 0] = __float2bfloat16(v.x);
    out[i + 1] = __float2bfloat16(v.y);
    out[i + 2] = __float2bfloat16(v.z);
    out[i + 3] = __float2bfloat16(v.w);
}

// W [8][K][64] -> Wt [8][64][K] bf16
__global__ void prep_w8_kernel(const float* __restrict__ W,
                               __hip_bfloat16* __restrict__ Wt, int K) {
    long i = (long)blockIdx.x * 256 + threadIdx.x;
    long tot = (long)HEADS * K * 64;
    if (i >= tot) return;
    int n = i & 63;
    long rest = i >> 6;
    int k = (int)(rest % K);
    int h = (int)(rest / K);
    Wt[((long)h * 64 + n) * K + k] = __float2bfloat16(W[i]);
}

// Wout [512][40] -> Wt [64][512] bf16, rows 40..63 zero
__global__ void prep_wout_kernel(const float* __restrict__ W,
                                 __hip_bfloat16* __restrict__ Wt) {
    int i = blockIdx.x * 256 + threadIdx.x;
    if (i >= 64 * 512) return;
    int k = i & 511;
    int n = i >> 9;
    Wt[i] = __float2bfloat16(n < OUTC ? W[(long)k * OUTC + n] : 0.f);
}

// ---------------- bf16 MFMA GEMM ----------------
// C fp32 always; Cb (bf16 mirror) written when non-null (used by agg gather).

__global__ __launch_bounds__(256) void gemm_mfma(
    const __hip_bfloat16* __restrict__ A, const __hip_bfloat16* __restrict__ Bt,
    float* __restrict__ C, __hip_bfloat16* __restrict__ Cb,
    int M, int K, int NcolsTot) {
    constexpr int LDA = 40;                 // pad 32->40: 2-way bank max (free)
    __shared__ __hip_bfloat16 As[128 * LDA];
    __shared__ __hip_bfloat16 Bs[64 * LDA];
    int tid = threadIdx.x;
    int m0 = blockIdx.x * 128;
    const __hip_bfloat16* Bth = Bt + (long)blockIdx.y * 64 * K;
    int col0 = blockIdx.y * 64;
    int lane = tid & 63, wave = tid >> 6;
    int wm = wave * 32;
    int arow = tid >> 2, acol = (tid & 3) * 8;
    int fr = lane & 15, fq = lane >> 4;

    f32x4 acc[2][4] = {};

    for (int k0 = 0; k0 < K; k0 += 32) {
        int ma = min(m0 + arow, M - 1);
        int mb = min(m0 + 64 + arow, M - 1);
        float4 av1 = *(const float4*)(A + (long)ma * K + k0 + acol);
        float4 av2 = *(const float4*)(A + (long)mb * K + k0 + acol);
        float4 bv  = *(const float4*)(Bth + (long)arow * K + k0 + acol);
        __syncthreads();
        *(float4*)(As + arow * LDA + acol) = av1;
        *(float4*)(As + (64 + arow) * LDA + acol) = av2;
        *(float4*)(Bs + arow * LDA + acol) = bv;
        __syncthreads();
        bf16x8 a0 = *(const bf16x8*)(As + (wm + fr) * LDA + fq * 8);
        bf16x8 a1 = *(const bf16x8*)(As + (wm + 16 + fr) * LDA + fq * 8);
        #pragma unroll
        for (int ni = 0; ni < 4; ni++) {
            bf16x8 b = *(const bf16x8*)(Bs + (ni * 16 + fr) * LDA + fq * 8);
            acc[0][ni] = __builtin_amdgcn_mfma_f32_16x16x32_bf16(a0, b, acc[0][ni], 0, 0, 0);
            acc[1][ni] = __builtin_amdgcn_mfma_f32_16x16x32_bf16(a1, b, acc[1][ni], 0, 0, 0);
        }
    }

    #pragma unroll
    for (int mi = 0; mi < 2; mi++)
        #pragma unroll
        for (int ni = 0; ni < 4; ni++)
            #pragma unroll
            for (int rr = 0; rr < 4; rr++) {
                int m = m0 + wm + mi * 16 + fq * 4 + rr;
                int n = col0 + ni * 16 + fr;
                if (m < M && n < NcolsTot) {
                    float v = acc[mi][ni][rr];
                    C[(long)m * NcolsTot + n] = v;
                    if (Cb) Cb[(long)m * NcolsTot + n] = __float2bfloat16(v);
                }
            }
}

// ---------------- attention scores ----------------

__global__ __launch_bounds__(256) void scores8_kernel(
    const float* __restrict__ Wh, const float* __restrict__ a,
    float* __restrict__ ssrc, float* __restrict__ sdst, int N) {
    int wid = blockIdx.x * 4 + (threadIdx.x >> 6);
    if (wid >= N * HEADS) return;
    int node = wid >> 3, head = wid & 7, lane = threadIdx.x & 63;
    float w = Wh[(long)node * F1 + head * HID + lane];
    float ss = w * a[head * 2 * HID + lane];
    float sd = w * a[head * 2 * HID + HID + lane];
    #pragma unroll
    for (int o = 32; o; o >>= 1) {
        ss += __shfl_xor(ss, o);
        sd += __shfl_xor(sd, o);
    }
    if (lane == 0) {
        ssrc[node * HEADS + head] = ss;
        sdst[node * HEADS + head] = sd;
    }
}

__global__ __launch_bounds__(256) void scores1_kernel(
    const float* __restrict__ Wh, const float* __restrict__ a,
    float* __restrict__ ssrc, float* __restrict__ sdst, int N) {
    int node = blockIdx.x * 4 + (threadIdx.x >> 6);
    if (node >= N) return;
    int lane = threadIdx.x & 63;
    float w = (lane < OUTC) ? Wh[(long)node * OUTC + lane] : 0.f;
    float ss = (lane < OUTC) ? w * a[lane] : 0.f;
    float sd = (lane < OUTC) ? w * a[OUTC + lane] : 0.f;
    #pragma unroll
    for (int o = 32; o; o >>= 1) {
        ss += __shfl_xor(ss, o);
        sd += __shfl_xor(sd, o);
    }
    if (lane == 0) {
        ssrc[node] = ss;
        sdst[node] = sd;
    }
}

// ---------------- aggregation (edge-dim parallel, bf16 gather) ----------------

__global__ __launch_bounds__(256) void agg8_kernel(
    const __hip_bfloat16* __restrict__ Whb, const float* __restrict__ ssrc,
    const float* __restrict__ sdst, const int* __restrict__ csr,
    const int* __restrict__ indptr, __hip_bfloat16* __restrict__ H, int N) {
    int wid = blockIdx.x * 4 + (threadIdx.x >> 6);
    if (wid >= N * HEADS) return;
    int node = wid >> 3, head = wid & 7, lane = threadIdx.x & 63;
    int s = __builtin_amdgcn_readfirstlane(indptr[node]);
    int e = __builtin_amdgcn_readfirstlane(indptr[node + 1]);
    float sd = sdst[node * HEADS + head];
    const __hip_bfloat16* whb = Whb + head * HID + lane;

    float m_run = -1e30f, d_run = 0.f, acc = 0.f;
    for (int t = s; t < e; t += 64) {
        int cnt = min(64, e - t);
        int src_i = node;
        float x_i = -1e30f;
        if (lane < cnt) {
            src_i = csr[t + lane];
            float x = ssrc[src_i * HEADS + head] + sd;
            x_i = x > 0.f ? x : ALPHA_SLOPE * x;
        }
        float tm = x_i;
        #pragma unroll
        for (int o = 32; o; o >>= 1) tm = fmaxf(tm, __shfl_xor(tm, o));
        float nm = fmaxf(m_run, tm);
        float scale = __expf(m_run - nm);
        acc *= scale; d_run *= scale;
        m_run = nm;
        float w_i = __expf(x_i - nm);
        float ts = w_i;
        #pragma unroll
        for (int o = 32; o; o >>= 1) ts += __shfl_xor(ts, o);
        d_run += ts;
        int cnt4 = (cnt + 3) & ~3;
        for (int j = 0; j < cnt4; j += 4) {
            #pragma unroll
            for (int u = 0; u < 4; u++) {
                int   sj = __shfl(src_i, j + u);
                float wj = __shfl(w_i,  j + u);
                unsigned off = (unsigned)sj * (unsigned)F1;   // < 2^25, 32-bit safe
                acc += wj * __bfloat162float(whb[off]);
            }
        }
    }
    float v = acc / d_run;
    v = v > 0.f ? v : (__expf(v) - 1.f);   // ELU (concat layer)
    H[(long)node * F1 + head * HID + lane] = __float2bfloat16(v);
}

__global__ __launch_bounds__(256) void aggout_kernel(
    const float* __restrict__ Wh, const float* __restrict__ ssrc,
    const float* __restrict__ sdst, const int* __restrict__ csr,
    const int* __restrict__ indptr, float* __restrict__ out, int N) {
    int node = blockIdx.x * 4 + (threadIdx.x >> 6);
    if (node >= N) return;
    int lane = threadIdx.x & 63;
    int s = __builtin_amdgcn_readfirstlane(indptr[node]);
    int e = __builtin_amdgcn_readfirstlane(indptr[node + 1]);
    float sd = sdst[node];
    int lc = min(lane, OUTC - 1);
    const float* whb = Wh + lc;

    float m_run = -1e30f, d_run = 0.f, acc = 0.f;
    for (int t = s; t < e; t += 64) {
        int cnt = min(64, e - t);
        int src_i = node;
        float x_i = -1e30f;
        if (lane < cnt) {
            src_i = csr[t + lane];
            float x = ssrc[src_i] + sd;
            x_i = x > 0.f ? x : ALPHA_SLOPE * x;
        }
        float tm = x_i;
        #pragma unroll
        for (int o = 32; o; o >>= 1) tm = fmaxf(tm, __shfl_xor(tm, o));
        float nm = fmaxf(m_run, tm);
        float scale = __expf(m_run - nm);
        acc *= scale; d_run *= scale;
        m_run = nm;
        float w_i = __expf(x_i - nm);
        float ts = w_i;
        #pragma unroll
        for (int o = 32; o; o >>= 1) ts += __shfl_xor(ts, o);
        d_run += ts;
        int cnt4 = (cnt + 3) & ~3;
        for (int j = 0; j < cnt4; j += 4) {
            #pragma unroll
            for (int u = 0; u < 4; u++) {
                int   sj = __shfl(src_i, j + u);
                float wj = __shfl(w_i,  j + u);
                acc += wj * whb[(long)sj * OUTC];
            }
        }
    }
    float g = acc / d_run;
    float v = g > 0.f ? g : (__expf(g) - 1.f);
    float vm = (lane < OUTC) ? v : -1e30f;
    #pragma unroll
    for (int o = 32; o; o >>= 1) vm = fmaxf(vm, __shfl_xor(vm, o));
    float ex = (lane < OUTC) ? __expf(v - vm) : 0.f;
    #pragma unroll
    for (int o = 32; o; o >>= 1) ex += __shfl_xor(ex, o);
    if (lane < OUTC) out[(long)node * OUTC + lane] = v - vm - logf(ex);
}

// ---------------- launch ----------------

extern "C" void kernel_launch(void* const* d_in, const int* in_sizes, int n_in,
                              void* d_out, int out_size, void* d_ws, size_t ws_size,
                              hipStream_t stream) {
    const float* x    = (const float*)d_in[0];
    const int*   ei   = (const int*)d_in[1];
    const float* W0   = (const float*)d_in[2];
    const float* a0   = (const float*)d_in[3];
    const float* W1   = (const float*)d_in[4];
    const float* a1   = (const float*)d_in[5];
    const float* Wout = (const float*)d_in[6];
    const float* aout = (const float*)d_in[7];
    float* out = (float*)d_out;

    const int N = in_sizes[0] / IN_F;
    const int E = in_sizes[1] / 2;
    const int Etot = E + N;
    const int* erow = ei;
    const int* ecol = ei + E;

    char* p = (char*)d_ws;
    auto carve = [&](size_t bytes) {
        void* r = (void*)p;
        p += (bytes + 255) & ~(size_t)255;
        return r;
    };
    float*           Wh   = (float*)carve((size_t)N * F1 * 4);       // fp32 GEMM out
    __hip_bfloat16*  Whb  = (__hip_bfloat16*)carve((size_t)N * F1 * 2); // bf16 mirror
    __hip_bfloat16*  Hb   = (__hip_bfloat16*)carve((size_t)N * F1 * 2); // layer output
    __hip_bfloat16*  xb   = (__hip_bfloat16*)carve((size_t)N * IN_F * 2);
    __hip_bfloat16*  Wt0  = (__hip_bfloat16*)carve((size_t)HEADS * 64 * IN_F * 2);
    __hip_bfloat16*  Wt1  = (__hip_bfloat16*)carve((size_t)HEADS * 64 * F1 * 2);
    __hip_bfloat16*  WtO  = (__hip_bfloat16*)carve((size_t)64 * F1 * 2);
    float*  ssrc   = (float*)carve((size_t)N * HEADS * 4);
    float*  sdst   = (float*)carve((size_t)N * HEADS * 4);
    int*    cnt    = (int*)carve((size_t)N * 4);
    int*    indptr = (int*)carve((size_t)(N + 1) * 4);
    int*    fill   = (int*)carve((size_t)N * 4);
    int*    csr    = (int*)carve((size_t)Etot * 4);

    // CSR build
    hipMemsetAsync(cnt, 0, (size_t)N * 4, stream);
    int eb = (Etot + 255) / 256;
    hist_kernel<<<eb, 256, 0, stream>>>(ecol, cnt, E, N);
    scan_kernel<<<1, 1024, 0, stream>>>(cnt, indptr, fill, N);
    scatter_kernel<<<eb, 256, 0, stream>>>(erow, ecol, fill, csr, E, N);

    // prep bf16 operands
    long nx = (long)N * IN_F;
    cvt_bf16_kernel<<<(int)((nx / 4 + 255) / 256), 256, 0, stream>>>(x, xb, nx);
    prep_w8_kernel<<<(HEADS * IN_F * 64 + 255) / 256, 256, 0, stream>>>(W0, Wt0, IN_F);
    prep_w8_kernel<<<(HEADS * F1 * 64 + 255) / 256, 256, 0, stream>>>(W1, Wt1, F1);
    prep_wout_kernel<<<(64 * 512 + 255) / 256, 256, 0, stream>>>(Wout, WtO);

    int mtiles = (N + 127) / 128;
    int wb8 = (N * HEADS + 3) / 4;
    int wb1 = (N + 3) / 4;

    // Layer 0
    gemm_mfma<<<dim3(mtiles, HEADS), 256, 0, stream>>>(xb, Wt0, Wh, Whb, N, IN_F, F1);
    scores8_kernel<<<wb8, 256, 0, stream>>>(Wh, a0, ssrc, sdst, N);
    agg8_kernel<<<wb8, 256, 0, stream>>>(Whb, ssrc, sdst, csr, indptr, Hb, N);

    // Layer 1
    gemm_mfma<<<dim3(mtiles, HEADS), 256, 0, stream>>>(Hb, Wt1, Wh, Whb, N, F1, F1);
    scores8_kernel<<<wb8, 256, 0, stream>>>(Wh, a1, ssrc, sdst, N);
    agg8_kernel<<<wb8, 256, 0, stream>>>(Whb, ssrc, sdst, csr, indptr, Hb, N);

    // Out layer
    gemm_mfma<<<dim3(mtiles, 1), 256, 0, stream>>>(Hb, WtO, Wh, (__hip_bfloat16*)nullptr,
                                                   N, F1, OUTC);
    scores1_kernel<<<wb1, 256, 0, stream>>>(Wh, aout, ssrc, sdst, N);
    aggout_kernel<<<wb1, 256, 0, stream>>>(Wh, ssrc, sdst, csr, indptr, out, N);
}

// Round 5
// 873.992 us; speedup vs baseline: 3.2141x; 1.1981x over previous
//
#include <hip/hip_runtime.h>
#include <hip/hip_bf16.h>

#define IN_F   256
#define HID    64
#define HEADS  8
#define OUTC   40
#define ALPHA_SLOPE 0.2f
#define F1     (HEADS*HID)   // 512

typedef short bf16x8 __attribute__((ext_vector_type(8)));
typedef float f32x4  __attribute__((ext_vector_type(4)));

// ---------------- CSR build ----------------

__global__ void hist_kernel(const int* __restrict__ col, int* __restrict__ cnt,
                            int E, int N) {
    int k = blockIdx.x * 256 + threadIdx.x;
    int tot = E + N;
    if (k >= tot) return;
    int c = (k < E) ? col[k] : (k - E);
    atomicAdd(&cnt[c], 1);
}

__global__ void scan_kernel(const int* __restrict__ cnt, int* __restrict__ indptr,
                            int* __restrict__ fill, int N) {
    __shared__ int sdata[1024];
    __shared__ int scarry;
    int tid = threadIdx.x;
    if (tid == 0) scarry = 0;
    __syncthreads();
    int ntiles = (N + 1023) >> 10;
    for (int t = 0; t < ntiles; t++) {
        int i = t * 1024 + tid;
        int v = (i < N) ? cnt[i] : 0;
        sdata[tid] = v;
        __syncthreads();
        for (int off = 1; off < 1024; off <<= 1) {
            int tv = (tid >= off) ? sdata[tid - off] : 0;
            __syncthreads();
            sdata[tid] += tv;
            __syncthreads();
        }
        int incl = sdata[tid];
        int carry = scarry;
        if (i < N) {
            int excl = carry + incl - v;
            indptr[i] = excl;
            fill[i] = excl;
        }
        __syncthreads();
        if (tid == 0) scarry = carry + sdata[1023];
        __syncthreads();
    }
    if (tid == 0) indptr[N] = scarry;
}

__global__ void scatter_kernel(const int* __restrict__ row, const int* __restrict__ col,
                               int* __restrict__ fill, int* __restrict__ csr,
                               int E, int N) {
    int k = blockIdx.x * 256 + threadIdx.x;
    int tot = E + N;
    if (k >= tot) return;
    int c = (k < E) ? col[k] : (k - E);
    int r = (k < E) ? row[k] : (k - E);
    int pos = atomicAdd(&fill[c], 1);
    csr[pos] = r;
}

// ---------------- prep: fp32 -> bf16 converts / weight transposes ----------------

__global__ void cvt_bf16_kernel(const float* __restrict__ in,
                                __hip_bfloat16* __restrict__ out, long n) {
    long i = ((long)blockIdx.x * 256 + threadIdx.x) * 4;
    if (i + 3 >= n) {
        for (long j = i; j < n; j++) out[j] = __float2bfloat16(in[j]);
        return;
    }
    float4 v = *(const float4*)(in + i);
    out[i + 0] = __float2bfloat16(v.x);
    out[i + 1] = __float2bfloat16(v.y);
    out[i + 2] = __float2bfloat16(v.z);
    out[i + 3] = __float2bfloat16(v.w);
}

// W [8][K][64] -> Wt [8][64][K] bf16
__global__ void prep_w8_kernel(const float* __restrict__ W,
                               __hip_bfloat16* __restrict__ Wt, int K) {
    long i = (long)blockIdx.x * 256 + threadIdx.x;
    long tot = (long)HEADS * K * 64;
    if (i >= tot) return;
    int n = i & 63;
    long rest = i >> 6;
    int k = (int)(rest % K);
    int h = (int)(rest / K);
    Wt[((long)h * 64 + n) * K + k] = __float2bfloat16(W[i]);
}

// Wout [512][40] -> Wt [64][512] bf16, rows 40..63 zero
__global__ void prep_wout_kernel(const float* __restrict__ W,
                                 __hip_bfloat16* __restrict__ Wt) {
    int i = blockIdx.x * 256 + threadIdx.x;
    if (i >= 64 * 512) return;
    int k = i & 511;
    int n = i >> 9;
    Wt[i] = __float2bfloat16(n < OUTC ? W[(long)k * OUTC + n] : 0.f);
}

// ---------------- bf16 MFMA GEMM ----------------

__global__ __launch_bounds__(256) void gemm_mfma(
    const __hip_bfloat16* __restrict__ A, const __hip_bfloat16* __restrict__ Bt,
    float* __restrict__ C, __hip_bfloat16* __restrict__ Cb,
    int M, int K, int NcolsTot) {
    constexpr int LDA = 40;                 // pad 32->40: 2-way bank max (free)
    __shared__ __hip_bfloat16 As[128 * LDA];
    __shared__ __hip_bfloat16 Bs[64 * LDA];
    int tid = threadIdx.x;
    int m0 = blockIdx.x * 128;
    const __hip_bfloat16* Bth = Bt + (long)blockIdx.y * 64 * K;
    int col0 = blockIdx.y * 64;
    int lane = tid & 63, wave = tid >> 6;
    int wm = wave * 32;
    int arow = tid >> 2, acol = (tid & 3) * 8;
    int fr = lane & 15, fq = lane >> 4;

    f32x4 acc[2][4] = {};

    for (int k0 = 0; k0 < K; k0 += 32) {
        int ma = min(m0 + arow, M - 1);
        int mb = min(m0 + 64 + arow, M - 1);
        float4 av1 = *(const float4*)(A + (long)ma * K + k0 + acol);
        float4 av2 = *(const float4*)(A + (long)mb * K + k0 + acol);
        float4 bv  = *(const float4*)(Bth + (long)arow * K + k0 + acol);
        __syncthreads();
        *(float4*)(As + arow * LDA + acol) = av1;
        *(float4*)(As + (64 + arow) * LDA + acol) = av2;
        *(float4*)(Bs + arow * LDA + acol) = bv;
        __syncthreads();
        bf16x8 a0 = *(const bf16x8*)(As + (wm + fr) * LDA + fq * 8);
        bf16x8 a1 = *(const bf16x8*)(As + (wm + 16 + fr) * LDA + fq * 8);
        #pragma unroll
        for (int ni = 0; ni < 4; ni++) {
            bf16x8 b = *(const bf16x8*)(Bs + (ni * 16 + fr) * LDA + fq * 8);
            acc[0][ni] = __builtin_amdgcn_mfma_f32_16x16x32_bf16(a0, b, acc[0][ni], 0, 0, 0);
            acc[1][ni] = __builtin_amdgcn_mfma_f32_16x16x32_bf16(a1, b, acc[1][ni], 0, 0, 0);
        }
    }

    #pragma unroll
    for (int mi = 0; mi < 2; mi++)
        #pragma unroll
        for (int ni = 0; ni < 4; ni++)
            #pragma unroll
            for (int rr = 0; rr < 4; rr++) {
                int m = m0 + wm + mi * 16 + fq * 4 + rr;
                int n = col0 + ni * 16 + fr;
                if (m < M && n < NcolsTot) {
                    float v = acc[mi][ni][rr];
                    C[(long)m * NcolsTot + n] = v;
                    if (Cb) Cb[(long)m * NcolsTot + n] = __float2bfloat16(v);
                }
            }
}

// ---------------- attention scores ----------------

__global__ __launch_bounds__(256) void scores8_kernel(
    const float* __restrict__ Wh, const float* __restrict__ a,
    float* __restrict__ ssrc, float* __restrict__ sdst, int N) {
    int wid = blockIdx.x * 4 + (threadIdx.x >> 6);
    if (wid >= N * HEADS) return;
    int node = wid >> 3, head = wid & 7, lane = threadIdx.x & 63;
    float w = Wh[(long)node * F1 + head * HID + lane];
    float ss = w * a[head * 2 * HID + lane];
    float sd = w * a[head * 2 * HID + HID + lane];
    #pragma unroll
    for (int o = 32; o; o >>= 1) {
        ss += __shfl_xor(ss, o);
        sd += __shfl_xor(sd, o);
    }
    if (lane == 0) {
        ssrc[node * HEADS + head] = ss;
        sdst[node * HEADS + head] = sd;
    }
}

__global__ __launch_bounds__(256) void scores1_kernel(
    const float* __restrict__ Wh, const float* __restrict__ a,
    float* __restrict__ ssrc, float* __restrict__ sdst, int N) {
    int node = blockIdx.x * 4 + (threadIdx.x >> 6);
    if (node >= N) return;
    int lane = threadIdx.x & 63;
    float w = (lane < OUTC) ? Wh[(long)node * OUTC + lane] : 0.f;
    float ss = (lane < OUTC) ? w * a[lane] : 0.f;
    float sd = (lane < OUTC) ? w * a[OUTC + lane] : 0.f;
    #pragma unroll
    for (int o = 32; o; o >>= 1) {
        ss += __shfl_xor(ss, o);
        sd += __shfl_xor(sd, o);
    }
    if (lane == 0) {
        ssrc[node] = ss;
        sdst[node] = sd;
    }
}

// ---------------- aggregation: one wave per node, ALL 8 heads ----------------
// Lane = h*8 + f8: head h = lane>>3, feature octet f8 = lane&7 (features f8*8..+7).
// Phase 1 per 8-edge tile: lane (h, e8=lane&7) scores edge jb+e8 for head h;
// shfl_xor(1,2,4) reduces over e8 within each head group. Phase 2: per edge u,
// scalar src (readlane), each lane loads dwordx4 = 8 bf16 of its (head, octet) —
// the wave gathers the full 1 KB row once for all 8 heads. No epilogue reduction.

__global__ __launch_bounds__(256) void agg8_kernel(
    const __hip_bfloat16* __restrict__ Whb, const float* __restrict__ ssrc,
    const float* __restrict__ sdst, const int* __restrict__ csr,
    const int* __restrict__ indptr, __hip_bfloat16* __restrict__ H, int N) {
    int node = blockIdx.x * 4 + (threadIdx.x >> 6);
    if (node >= N) return;
    int lane = threadIdx.x & 63;
    int h = lane >> 3;
    int e8 = lane & 7;
    int base_h = lane & 56;          // h*8
    int s = __builtin_amdgcn_readfirstlane(indptr[node]);
    int e = __builtin_amdgcn_readfirstlane(indptr[node + 1]);
    float sd = sdst[node * HEADS + h];

    float acc[8] = {};
    float m_run = -1e30f, d_run = 0.f;

    for (int jb = s; jb < e; jb += 8) {
        int cnt = min(8, e - jb);
        int src_i = 0;
        float x_i = -1e30f;
        if (e8 < cnt) {
            src_i = csr[jb + e8];
            float x = ssrc[src_i * HEADS + h] + sd;
            x_i = x > 0.f ? x : ALPHA_SLOPE * x;
        }
        float tm = x_i;
        tm = fmaxf(tm, __shfl_xor(tm, 1));
        tm = fmaxf(tm, __shfl_xor(tm, 2));
        tm = fmaxf(tm, __shfl_xor(tm, 4));
        float nm = fmaxf(m_run, tm);
        float scale = __expf(m_run - nm);
        #pragma unroll
        for (int k = 0; k < 8; k++) acc[k] *= scale;
        d_run *= scale;
        m_run = nm;
        float w_i = __expf(x_i - nm);        // 0 for invalid lanes
        float ts = w_i;
        ts += __shfl_xor(ts, 1);
        ts += __shfl_xor(ts, 2);
        ts += __shfl_xor(ts, 4);
        d_run += ts;
        for (int u = 0; u < cnt; u++) {
            float wj = __shfl(w_i, base_h + u);          // per-head weight
            int   su = __shfl(src_i, u);                 // uniform -> scalar
            const uint4* rp = (const uint4*)(Whb + (long)su * F1 + lane * 8);
            uint4 d = *rp;
            acc[0] += wj * __uint_as_float(d.x << 16);
            acc[1] += wj * __uint_as_float(d.x & 0xffff0000u);
            acc[2] += wj * __uint_as_float(d.y << 16);
            acc[3] += wj * __uint_as_float(d.y & 0xffff0000u);
            acc[4] += wj * __uint_as_float(d.z << 16);
            acc[5] += wj * __uint_as_float(d.z & 0xffff0000u);
            acc[6] += wj * __uint_as_float(d.w << 16);
            acc[7] += wj * __uint_as_float(d.w & 0xffff0000u);
        }
    }

    float inv = 1.f / d_run;
    unsigned short us[8];
    #pragma unroll
    for (int k = 0; k < 8; k++) {
        float v = acc[k] * inv;
        v = v > 0.f ? v : (__expf(v) - 1.f);   // ELU
        __hip_bfloat16 b = __float2bfloat16(v);
        __builtin_memcpy(&us[k], &b, 2);
    }
    uint4 ov;
    __builtin_memcpy(&ov, us, 16);
    *(uint4*)(H + (long)node * F1 + lane * 8) = ov;
}

__global__ __launch_bounds__(256) void aggout_kernel(
    const float* __restrict__ Wh, const float* __restrict__ ssrc,
    const float* __restrict__ sdst, const int* __restrict__ csr,
    const int* __restrict__ indptr, float* __restrict__ out, int N) {
    int node = blockIdx.x * 4 + (threadIdx.x >> 6);
    if (node >= N) return;
    int lane = threadIdx.x & 63;
    int s = __builtin_amdgcn_readfirstlane(indptr[node]);
    int e = __builtin_amdgcn_readfirstlane(indptr[node + 1]);
    float sd = sdst[node];
    int lc = min(lane, OUTC - 1);
    const float* whb = Wh + lc;

    float m_run = -1e30f, d_run = 0.f, acc = 0.f;
    for (int t = s; t < e; t += 64) {
        int cnt = min(64, e - t);
        int src_i = node;
        float x_i = -1e30f;
        if (lane < cnt) {
            src_i = csr[t + lane];
            float x = ssrc[src_i] + sd;
            x_i = x > 0.f ? x : ALPHA_SLOPE * x;
        }
        float tm = x_i;
        #pragma unroll
        for (int o = 32; o; o >>= 1) tm = fmaxf(tm, __shfl_xor(tm, o));
        float nm = fmaxf(m_run, tm);
        float scale = __expf(m_run - nm);
        acc *= scale; d_run *= scale;
        m_run = nm;
        float w_i = __expf(x_i - nm);
        float ts = w_i;
        #pragma unroll
        for (int o = 32; o; o >>= 1) ts += __shfl_xor(ts, o);
        d_run += ts;
        int cnt4 = (cnt + 3) & ~3;
        for (int j = 0; j < cnt4; j += 4) {
            #pragma unroll
            for (int u = 0; u < 4; u++) {
                int   sj = __shfl(src_i, j + u);
                float wj = __shfl(w_i,  j + u);
                acc += wj * whb[(long)sj * OUTC];
            }
        }
    }
    float g = acc / d_run;
    float v = g > 0.f ? g : (__expf(g) - 1.f);
    float vm = (lane < OUTC) ? v : -1e30f;
    #pragma unroll
    for (int o = 32; o; o >>= 1) vm = fmaxf(vm, __shfl_xor(vm, o));
    float ex = (lane < OUTC) ? __expf(v - vm) : 0.f;
    #pragma unroll
    for (int o = 32; o; o >>= 1) ex += __shfl_xor(ex, o);
    if (lane < OUTC) out[(long)node * OUTC + lane] = v - vm - logf(ex);
}

// ---------------- launch ----------------

extern "C" void kernel_launch(void* const* d_in, const int* in_sizes, int n_in,
                              void* d_out, int out_size, void* d_ws, size_t ws_size,
                              hipStream_t stream) {
    const float* x    = (const float*)d_in[0];
    const int*   ei   = (const int*)d_in[1];
    const float* W0   = (const float*)d_in[2];
    const float* a0   = (const float*)d_in[3];
    const float* W1   = (const float*)d_in[4];
    const float* a1   = (const float*)d_in[5];
    const float* Wout = (const float*)d_in[6];
    const float* aout = (const float*)d_in[7];
    float* out = (float*)d_out;

    const int N = in_sizes[0] / IN_F;
    const int E = in_sizes[1] / 2;
    const int Etot = E + N;
    const int* erow = ei;
    const int* ecol = ei + E;

    char* p = (char*)d_ws;
    auto carve = [&](size_t bytes) {
        void* r = (void*)p;
        p += (bytes + 255) & ~(size_t)255;
        return r;
    };
    float*           Wh   = (float*)carve((size_t)N * F1 * 4);
    __hip_bfloat16*  Whb  = (__hip_bfloat16*)carve((size_t)N * F1 * 2);
    __hip_bfloat16*  Hb   = (__hip_bfloat16*)carve((size_t)N * F1 * 2);
    __hip_bfloat16*  xb   = (__hip_bfloat16*)carve((size_t)N * IN_F * 2);
    __hip_bfloat16*  Wt0  = (__hip_bfloat16*)carve((size_t)HEADS * 64 * IN_F * 2);
    __hip_bfloat16*  Wt1  = (__hip_bfloat16*)carve((size_t)HEADS * 64 * F1 * 2);
    __hip_bfloat16*  WtO  = (__hip_bfloat16*)carve((size_t)64 * F1 * 2);
    float*  ssrc   = (float*)carve((size_t)N * HEADS * 4);
    float*  sdst   = (float*)carve((size_t)N * HEADS * 4);
    int*    cnt    = (int*)carve((size_t)N * 4);
    int*    indptr = (int*)carve((size_t)(N + 1) * 4);
    int*    fill   = (int*)carve((size_t)N * 4);
    int*    csr    = (int*)carve((size_t)Etot * 4);

    // CSR build
    hipMemsetAsync(cnt, 0, (size_t)N * 4, stream);
    int eb = (Etot + 255) / 256;
    hist_kernel<<<eb, 256, 0, stream>>>(ecol, cnt, E, N);
    scan_kernel<<<1, 1024, 0, stream>>>(cnt, indptr, fill, N);
    scatter_kernel<<<eb, 256, 0, stream>>>(erow, ecol, fill, csr, E, N);

    // prep bf16 operands
    long nx = (long)N * IN_F;
    cvt_bf16_kernel<<<(int)((nx / 4 + 255) / 256), 256, 0, stream>>>(x, xb, nx);
    prep_w8_kernel<<<(HEADS * IN_F * 64 + 255) / 256, 256, 0, stream>>>(W0, Wt0, IN_F);
    prep_w8_kernel<<<(HEADS * F1 * 64 + 255) / 256, 256, 0, stream>>>(W1, Wt1, F1);
    prep_wout_kernel<<<(64 * 512 + 255) / 256, 256, 0, stream>>>(Wout, WtO);

    int mtiles = (N + 127) / 128;
    int wb8 = (N * HEADS + 3) / 4;
    int wb1 = (N + 3) / 4;

    // Layer 0
    gemm_mfma<<<dim3(mtiles, HEADS), 256, 0, stream>>>(xb, Wt0, Wh, Whb, N, IN_F, F1);
    scores8_kernel<<<wb8, 256, 0, stream>>>(Wh, a0, ssrc, sdst, N);
    agg8_kernel<<<wb1, 256, 0, stream>>>(Whb, ssrc, sdst, csr, indptr, Hb, N);

    // Layer 1
    gemm_mfma<<<dim3(mtiles, HEADS), 256, 0, stream>>>(Hb, Wt1, Wh, Whb, N, F1, F1);
    scores8_kernel<<<wb8, 256, 0, stream>>>(Wh, a1, ssrc, sdst, N);
    agg8_kernel<<<wb1, 256, 0, stream>>>(Whb, ssrc, sdst, csr, indptr, Hb, N);

    // Out layer
    gemm_mfma<<<dim3(mtiles, 1), 256, 0, stream>>>(Hb, WtO, Wh, (__hip_bfloat16*)nullptr,
                                                   N, F1, OUTC);
    scores1_kernel<<<wb1, 256, 0, stream>>>(Wh, aout, ssrc, sdst, N);
    aggout_kernel<<<wb1, 256, 0, stream>>>(Wh, ssrc, sdst, csr, indptr, out, N);
}

// Round 6
// 726.353 us; speedup vs baseline: 3.8674x; 1.2033x over previous
//
#include <hip/hip_runtime.h>
#include <hip/hip_bf16.h>

#define IN_F   256
#define HID    64
#define HEADS  8
#define OUTC   40
#define ALPHA_SLOPE 0.2f
#define F1     (HEADS*HID)   // 512

typedef short bf16x8 __attribute__((ext_vector_type(8)));
typedef float f32x4  __attribute__((ext_vector_type(4)));

// ---------------- CSR build ----------------

__global__ void hist_kernel(const int* __restrict__ col, int* __restrict__ cnt,
                            int E, int N) {
    int k = blockIdx.x * 256 + threadIdx.x;
    int tot = E + N;
    if (k >= tot) return;
    int c = (k < E) ? col[k] : (k - E);
    atomicAdd(&cnt[c], 1);
}

// parallel scan: (1) per-1024 block scan, (2) scan of block sums (<=64 blocks),
// (3) add offsets

__global__ __launch_bounds__(1024) void scan1_kernel(
    const int* __restrict__ cnt, int* __restrict__ excl,
    int* __restrict__ bsum, int N) {
    __shared__ int wsum[16];
    int tid = threadIdx.x;
    int i = blockIdx.x * 1024 + tid;
    int lane = tid & 63, wid = tid >> 6;
    int v = (i < N) ? cnt[i] : 0;
    int incl = v;
    #pragma unroll
    for (int off = 1; off < 64; off <<= 1) {
        int t = __shfl_up(incl, off);
        if (lane >= off) incl += t;
    }
    if (lane == 63) wsum[wid] = incl;
    __syncthreads();
    if (wid == 0) {
        int w = (lane < 16) ? wsum[lane] : 0;
        #pragma unroll
        for (int off = 1; off < 16; off <<= 1) {
            int t = __shfl_up(w, off);
            if (lane >= off) w += t;
        }
        if (lane < 16) wsum[lane] = w;
    }
    __syncthreads();
    int woff = (wid > 0) ? wsum[wid - 1] : 0;
    int e = woff + incl - v;
    if (i < N) excl[i] = e;
    if (tid == 1023) bsum[blockIdx.x] = woff + incl;
}

__global__ void scan2_kernel(const int* __restrict__ bsum, int* __restrict__ boff,
                             int* __restrict__ indptrN, int nb) {
    int lane = threadIdx.x;
    int v = (lane < nb) ? bsum[lane] : 0;
    int incl = v;
    #pragma unroll
    for (int off = 1; off < 64; off <<= 1) {
        int t = __shfl_up(incl, off);
        if (lane >= off) incl += t;
    }
    if (lane < nb) boff[lane] = incl - v;
    if (lane == 63) *indptrN = incl;
}

__global__ void scan3_kernel(const int* __restrict__ boff, int* __restrict__ indptr,
                             int* __restrict__ fill, int N) {
    int i = blockIdx.x * 256 + threadIdx.x;
    if (i >= N) return;
    int e = indptr[i] + boff[i >> 10];
    indptr[i] = e;
    fill[i] = e;
}

__global__ void scatter_kernel(const int* __restrict__ row, const int* __restrict__ col,
                               int* __restrict__ fill, int* __restrict__ csr,
                               int E, int N) {
    int k = blockIdx.x * 256 + threadIdx.x;
    int tot = E + N;
    if (k >= tot) return;
    int c = (k < E) ? col[k] : (k - E);
    int r = (k < E) ? row[k] : (k - E);
    int pos = atomicAdd(&fill[c], 1);
    csr[pos] = r;
}

// ---------------- prep: fp32 -> bf16 converts / weight transposes ----------------

__global__ void cvt_bf16_kernel(const float* __restrict__ in,
                                __hip_bfloat16* __restrict__ out, long n) {
    long i = ((long)blockIdx.x * 256 + threadIdx.x) * 4;
    if (i + 3 >= n) {
        for (long j = i; j < n; j++) out[j] = __float2bfloat16(in[j]);
        return;
    }
    float4 v = *(const float4*)(in + i);
    out[i + 0] = __float2bfloat16(v.x);
    out[i + 1] = __float2bfloat16(v.y);
    out[i + 2] = __float2bfloat16(v.z);
    out[i + 3] = __float2bfloat16(v.w);
}

// W [8][K][64] -> Wt [512][K] bf16  (row n = h*64+f holds W[h][:,f])
__global__ void prep_w8_kernel(const float* __restrict__ W,
                               __hip_bfloat16* __restrict__ Wt, int K) {
    long i = (long)blockIdx.x * 256 + threadIdx.x;
    long tot = (long)HEADS * K * 64;
    if (i >= tot) return;
    int n = i & 63;
    long rest = i >> 6;
    int k = (int)(rest % K);
    int h = (int)(rest / K);
    Wt[((long)h * 64 + n) * K + k] = __float2bfloat16(W[i]);
}

// Wout [512][40] -> Wt [64][512] bf16, rows 40..63 zero
__global__ void prep_wout_kernel(const float* __restrict__ W,
                                 __hip_bfloat16* __restrict__ Wt) {
    int i = blockIdx.x * 256 + threadIdx.x;
    if (i >= 64 * 512) return;
    int k = i & 511;
    int n = i >> 9;
    Wt[i] = __float2bfloat16(n < OUTC ? W[(long)k * OUTC + n] : 0.f);
}

// ---------------- dense 128x128 bf16 MFMA GEMM (bf16 output) ----------------
// C[M,512] = A[M,K] @ Bt^T. grid = (ceil(M/128), 4). Wave grid 2x2 of 64x64.

__global__ __launch_bounds__(256) void gemm128(
    const __hip_bfloat16* __restrict__ A, const __hip_bfloat16* __restrict__ Bt,
    __hip_bfloat16* __restrict__ Cb, int M, int K) {
    constexpr int LDA = 40;
    __shared__ __hip_bfloat16 As[128 * LDA];
    __shared__ __hip_bfloat16 Bs[128 * LDA];
    int tid = threadIdx.x;
    int m0 = blockIdx.x * 128;
    int n0 = blockIdx.y * 128;
    int lane = tid & 63, wave = tid >> 6;
    int wm = (wave & 1) * 64, wn = (wave >> 1) * 64;
    int fr = lane & 15, fq = lane >> 4;
    int srow = tid >> 1, scol = (tid & 1) * 16;

    const __hip_bfloat16* Arow = A + (long)min(m0 + srow, M - 1) * K;
    const __hip_bfloat16* Brow = Bt + (long)(n0 + srow) * K;

    f32x4 acc[4][4] = {};

    for (int k0 = 0; k0 < K; k0 += 32) {
        float4 av0 = *(const float4*)(Arow + k0 + scol);
        float4 av1 = *(const float4*)(Arow + k0 + scol + 8);
        float4 bv0 = *(const float4*)(Brow + k0 + scol);
        float4 bv1 = *(const float4*)(Brow + k0 + scol + 8);
        __syncthreads();
        *(float4*)(As + srow * LDA + scol) = av0;
        *(float4*)(As + srow * LDA + scol + 8) = av1;
        *(float4*)(Bs + srow * LDA + scol) = bv0;
        *(float4*)(Bs + srow * LDA + scol + 8) = bv1;
        __syncthreads();
        bf16x8 af[4], bfr[4];
        #pragma unroll
        for (int mi = 0; mi < 4; mi++)
            af[mi] = *(const bf16x8*)(As + (wm + mi * 16 + fr) * LDA + fq * 8);
        #pragma unroll
        for (int ni = 0; ni < 4; ni++)
            bfr[ni] = *(const bf16x8*)(Bs + (wn + ni * 16 + fr) * LDA + fq * 8);
        #pragma unroll
        for (int mi = 0; mi < 4; mi++)
            #pragma unroll
            for (int ni = 0; ni < 4; ni++)
                acc[mi][ni] = __builtin_amdgcn_mfma_f32_16x16x32_bf16(
                    af[mi], bfr[ni], acc[mi][ni], 0, 0, 0);
    }

    #pragma unroll
    for (int mi = 0; mi < 4; mi++)
        #pragma unroll
        for (int ni = 0; ni < 4; ni++)
            #pragma unroll
            for (int rr = 0; rr < 4; rr++) {
                int m = m0 + wm + mi * 16 + fq * 4 + rr;
                int n = n0 + wn + ni * 16 + fr;
                if (m < M)
                    Cb[(long)m * F1 + n] = __float2bfloat16(acc[mi][ni][rr]);
            }
}

// ---------------- 64-wide MFMA GEMM for out layer (fp32 C [N,40]) ----------------

__global__ __launch_bounds__(256) void gemm_mfma(
    const __hip_bfloat16* __restrict__ A, const __hip_bfloat16* __restrict__ Bt,
    float* __restrict__ C, int M, int K, int NcolsTot) {
    constexpr int LDA = 40;
    __shared__ __hip_bfloat16 As[128 * LDA];
    __shared__ __hip_bfloat16 Bs[64 * LDA];
    int tid = threadIdx.x;
    int m0 = blockIdx.x * 128;
    int lane = tid & 63, wave = tid >> 6;
    int wm = wave * 32;
    int arow = tid >> 2, acol = (tid & 3) * 8;
    int fr = lane & 15, fq = lane >> 4;

    f32x4 acc[2][4] = {};

    for (int k0 = 0; k0 < K; k0 += 32) {
        int ma = min(m0 + arow, M - 1);
        int mb = min(m0 + 64 + arow, M - 1);
        float4 av1 = *(const float4*)(A + (long)ma * K + k0 + acol);
        float4 av2 = *(const float4*)(A + (long)mb * K + k0 + acol);
        float4 bv  = *(const float4*)(Bt + (long)arow * K + k0 + acol);
        __syncthreads();
        *(float4*)(As + arow * LDA + acol) = av1;
        *(float4*)(As + (64 + arow) * LDA + acol) = av2;
        *(float4*)(Bs + arow * LDA + acol) = bv;
        __syncthreads();
        bf16x8 a0 = *(const bf16x8*)(As + (wm + fr) * LDA + fq * 8);
        bf16x8 a1 = *(const bf16x8*)(As + (wm + 16 + fr) * LDA + fq * 8);
        #pragma unroll
        for (int ni = 0; ni < 4; ni++) {
            bf16x8 b = *(const bf16x8*)(Bs + (ni * 16 + fr) * LDA + fq * 8);
            acc[0][ni] = __builtin_amdgcn_mfma_f32_16x16x32_bf16(a0, b, acc[0][ni], 0, 0, 0);
            acc[1][ni] = __builtin_amdgcn_mfma_f32_16x16x32_bf16(a1, b, acc[1][ni], 0, 0, 0);
        }
    }

    #pragma unroll
    for (int mi = 0; mi < 2; mi++)
        #pragma unroll
        for (int ni = 0; ni < 4; ni++)
            #pragma unroll
            for (int rr = 0; rr < 4; rr++) {
                int m = m0 + wm + mi * 16 + fq * 4 + rr;
                int n = ni * 16 + fr;
                if (m < M && n < NcolsTot)
                    C[(long)m * NcolsTot + n] = acc[mi][ni][rr];
            }
}

// ---------------- attention scores ----------------

__global__ __launch_bounds__(256) void scores8_kernel(
    const __hip_bfloat16* __restrict__ Whb, const float* __restrict__ a,
    float* __restrict__ ssrc, float* __restrict__ sdst, int N) {
    int wid = blockIdx.x * 4 + (threadIdx.x >> 6);
    if (wid >= N * HEADS) return;
    int node = wid >> 3, head = wid & 7, lane = threadIdx.x & 63;
    float w = __bfloat162float(Whb[(long)node * F1 + head * HID + lane]);
    float ss = w * a[head * 2 * HID + lane];
    float sd = w * a[head * 2 * HID + HID + lane];
    #pragma unroll
    for (int o = 32; o; o >>= 1) {
        ss += __shfl_xor(ss, o);
        sd += __shfl_xor(sd, o);
    }
    if (lane == 0) {
        ssrc[node * HEADS + head] = ss;
        sdst[node * HEADS + head] = sd;
    }
}

__global__ __launch_bounds__(256) void scores1_kernel(
    const float* __restrict__ Wh, const float* __restrict__ a,
    float* __restrict__ ssrc, float* __restrict__ sdst, int N) {
    int node = blockIdx.x * 4 + (threadIdx.x >> 6);
    if (node >= N) return;
    int lane = threadIdx.x & 63;
    float w = (lane < OUTC) ? Wh[(long)node * OUTC + lane] : 0.f;
    float ss = (lane < OUTC) ? w * a[lane] : 0.f;
    float sd = (lane < OUTC) ? w * a[OUTC + lane] : 0.f;
    #pragma unroll
    for (int o = 32; o; o >>= 1) {
        ss += __shfl_xor(ss, o);
        sd += __shfl_xor(sd, o);
    }
    if (lane == 0) {
        ssrc[node] = ss;
        sdst[node] = sd;
    }
}

// ---------------- aggregation: one wave per node, ALL 8 heads ----------------

__global__ __launch_bounds__(256) void agg8_kernel(
    const __hip_bfloat16* __restrict__ Whb, const float* __restrict__ ssrc,
    const float* __restrict__ sdst, const int* __restrict__ csr,
    const int* __restrict__ indptr, __hip_bfloat16* __restrict__ H, int N) {
    int node = blockIdx.x * 4 + (threadIdx.x >> 6);
    if (node >= N) return;
    int lane = threadIdx.x & 63;
    int h = lane >> 3;
    int e8 = lane & 7;
    int base_h = lane & 56;
    int s = __builtin_amdgcn_readfirstlane(indptr[node]);
    int e = __builtin_amdgcn_readfirstlane(indptr[node + 1]);
    float sd = sdst[node * HEADS + h];

    float acc[8] = {};
    float m_run = -1e30f, d_run = 0.f;

    for (int jb = s; jb < e; jb += 8) {
        int cnt = min(8, e - jb);
        int src_i = 0;
        float x_i = -1e30f;
        if (e8 < cnt) {
            src_i = csr[jb + e8];
            float x = ssrc[src_i * HEADS + h] + sd;
            x_i = x > 0.f ? x : ALPHA_SLOPE * x;
        }
        float tm = x_i;
        tm = fmaxf(tm, __shfl_xor(tm, 1));
        tm = fmaxf(tm, __shfl_xor(tm, 2));
        tm = fmaxf(tm, __shfl_xor(tm, 4));
        float nm = fmaxf(m_run, tm);
        float scale = __expf(m_run - nm);
        #pragma unroll
        for (int k = 0; k < 8; k++) acc[k] *= scale;
        d_run *= scale;
        m_run = nm;
        float w_i = __expf(x_i - nm);
        float ts = w_i;
        ts += __shfl_xor(ts, 1);
        ts += __shfl_xor(ts, 2);
        ts += __shfl_xor(ts, 4);
        d_run += ts;
        for (int u = 0; u < cnt; u++) {
            float wj = __shfl(w_i, base_h + u);
            int   su = __shfl(src_i, u);
            const uint4* rp = (const uint4*)(Whb + (long)su * F1 + lane * 8);
            uint4 d = *rp;
            acc[0] += wj * __uint_as_float(d.x << 16);
            acc[1] += wj * __uint_as_float(d.x & 0xffff0000u);
            acc[2] += wj * __uint_as_float(d.y << 16);
            acc[3] += wj * __uint_as_float(d.y & 0xffff0000u);
            acc[4] += wj * __uint_as_float(d.z << 16);
            acc[5] += wj * __uint_as_float(d.z & 0xffff0000u);
            acc[6] += wj * __uint_as_float(d.w << 16);
            acc[7] += wj * __uint_as_float(d.w & 0xffff0000u);
        }
    }

    float inv = 1.f / d_run;
    unsigned short us[8];
    #pragma unroll
    for (int k = 0; k < 8; k++) {
        float v = acc[k] * inv;
        v = v > 0.f ? v : (__expf(v) - 1.f);
        __hip_bfloat16 b = __float2bfloat16(v);
        __builtin_memcpy(&us[k], &b, 2);
    }
    uint4 ov;
    __builtin_memcpy(&ov, us, 16);
    *(uint4*)(H + (long)node * F1 + lane * 8) = ov;
}

__global__ __launch_bounds__(256) void aggout_kernel(
    const float* __restrict__ Wh, const float* __restrict__ ssrc,
    const float* __restrict__ sdst, const int* __restrict__ csr,
    const int* __restrict__ indptr, float* __restrict__ out, int N) {
    int node = blockIdx.x * 4 + (threadIdx.x >> 6);
    if (node >= N) return;
    int lane = threadIdx.x & 63;
    int s = __builtin_amdgcn_readfirstlane(indptr[node]);
    int e = __builtin_amdgcn_readfirstlane(indptr[node + 1]);
    float sd = sdst[node];
    int lc = min(lane, OUTC - 1);
    const float* whb = Wh + lc;

    float m_run = -1e30f, d_run = 0.f, acc = 0.f;
    for (int t = s; t < e; t += 64) {
        int cnt = min(64, e - t);
        int src_i = node;
        float x_i = -1e30f;
        if (lane < cnt) {
            src_i = csr[t + lane];
            float x = ssrc[src_i] + sd;
            x_i = x > 0.f ? x : ALPHA_SLOPE * x;
        }
        float tm = x_i;
        #pragma unroll
        for (int o = 32; o; o >>= 1) tm = fmaxf(tm, __shfl_xor(tm, o));
        float nm = fmaxf(m_run, tm);
        float scale = __expf(m_run - nm);
        acc *= scale; d_run *= scale;
        m_run = nm;
        float w_i = __expf(x_i - nm);
        float ts = w_i;
        #pragma unroll
        for (int o = 32; o; o >>= 1) ts += __shfl_xor(ts, o);
        d_run += ts;
        int cnt4 = (cnt + 3) & ~3;
        for (int j = 0; j < cnt4; j += 4) {
            #pragma unroll
            for (int u = 0; u < 4; u++) {
                int   sj = __shfl(src_i, j + u);
                float wj = __shfl(w_i,  j + u);
                acc += wj * whb[(long)sj * OUTC];
            }
        }
    }
    float g = acc / d_run;
    float v = g > 0.f ? g : (__expf(g) - 1.f);
    float vm = (lane < OUTC) ? v : -1e30f;
    #pragma unroll
    for (int o = 32; o; o >>= 1) vm = fmaxf(vm, __shfl_xor(vm, o));
    float ex = (lane < OUTC) ? __expf(v - vm) : 0.f;
    #pragma unroll
    for (int o = 32; o; o >>= 1) ex += __shfl_xor(ex, o);
    if (lane < OUTC) out[(long)node * OUTC + lane] = v - vm - logf(ex);
}

// ---------------- launch ----------------

extern "C" void kernel_launch(void* const* d_in, const int* in_sizes, int n_in,
                              void* d_out, int out_size, void* d_ws, size_t ws_size,
                              hipStream_t stream) {
    const float* x    = (const float*)d_in[0];
    const int*   ei   = (const int*)d_in[1];
    const float* W0   = (const float*)d_in[2];
    const float* a0   = (const float*)d_in[3];
    const float* W1   = (const float*)d_in[4];
    const float* a1   = (const float*)d_in[5];
    const float* Wout = (const float*)d_in[6];
    const float* aout = (const float*)d_in[7];
    float* out = (float*)d_out;

    const int N = in_sizes[0] / IN_F;
    const int E = in_sizes[1] / 2;
    const int Etot = E + N;
    const int* erow = ei;
    const int* ecol = ei + E;

    char* p = (char*)d_ws;
    auto carve = [&](size_t bytes) {
        void* r = (void*)p;
        p += (bytes + 255) & ~(size_t)255;
        return r;
    };
    float*           Wh   = (float*)carve((size_t)N * OUTC * 4);      // out-layer fp32
    __hip_bfloat16*  Whb  = (__hip_bfloat16*)carve((size_t)N * F1 * 2);
    __hip_bfloat16*  Hb   = (__hip_bfloat16*)carve((size_t)N * F1 * 2);
    __hip_bfloat16*  xb   = (__hip_bfloat16*)carve((size_t)N * IN_F * 2);
    __hip_bfloat16*  Wt0  = (__hip_bfloat16*)carve((size_t)F1 * IN_F * 2);
    __hip_bfloat16*  Wt1  = (__hip_bfloat16*)carve((size_t)F1 * F1 * 2);
    __hip_bfloat16*  WtO  = (__hip_bfloat16*)carve((size_t)64 * F1 * 2);
    float*  ssrc   = (float*)carve((size_t)N * HEADS * 4);
    float*  sdst   = (float*)carve((size_t)N * HEADS * 4);
    int*    cnt    = (int*)carve((size_t)N * 4);
    int*    indptr = (int*)carve((size_t)(N + 1) * 4);
    int*    fill   = (int*)carve((size_t)N * 4);
    int*    csr    = (int*)carve((size_t)Etot * 4);
    int*    bsum   = (int*)carve(64 * 4);
    int*    boff   = (int*)carve(64 * 4);

    // CSR build
    hipMemsetAsync(cnt, 0, (size_t)N * 4, stream);
    int eb = (Etot + 255) / 256;
    int nb = (N + 1023) / 1024;   // 49 for N=50000 (<=64 required by scan2)
    hist_kernel<<<eb, 256, 0, stream>>>(ecol, cnt, E, N);
    scan1_kernel<<<nb, 1024, 0, stream>>>(cnt, indptr, bsum, N);
    scan2_kernel<<<1, 64, 0, stream>>>(bsum, boff, indptr + N, nb);
    scan3_kernel<<<(N + 255) / 256, 256, 0, stream>>>(boff, indptr, fill, N);
    scatter_kernel<<<eb, 256, 0, stream>>>(erow, ecol, fill, csr, E, N);

    // prep bf16 operands
    long nx = (long)N * IN_F;
    cvt_bf16_kernel<<<(int)((nx / 4 + 255) / 256), 256, 0, stream>>>(x, xb, nx);
    prep_w8_kernel<<<(HEADS * IN_F * 64 + 255) / 256, 256, 0, stream>>>(W0, Wt0, IN_F);
    prep_w8_kernel<<<(HEADS * F1 * 64 + 255) / 256, 256, 0, stream>>>(W1, Wt1, F1);
    prep_wout_kernel<<<(64 * 512 + 255) / 256, 256, 0, stream>>>(Wout, WtO);

    int mt128 = (N + 127) / 128;
    int wb8 = (N * HEADS + 3) / 4;
    int wb1 = (N + 3) / 4;

    // Layer 0
    gemm128<<<dim3(mt128, 4), 256, 0, stream>>>(xb, Wt0, Whb, N, IN_F);
    scores8_kernel<<<wb8, 256, 0, stream>>>(Whb, a0, ssrc, sdst, N);
    agg8_kernel<<<wb1, 256, 0, stream>>>(Whb, ssrc, sdst, csr, indptr, Hb, N);

    // Layer 1
    gemm128<<<dim3(mt128, 4), 256, 0, stream>>>(Hb, Wt1, Whb, N, F1);
    scores8_kernel<<<wb8, 256, 0, stream>>>(Whb, a1, ssrc, sdst, N);
    agg8_kernel<<<wb1, 256, 0, stream>>>(Whb, ssrc, sdst, csr, indptr, Hb, N);

    // Out layer
    gemm_mfma<<<dim3(mt128, 1), 256, 0, stream>>>(Hb, WtO, Wh, N, F1, OUTC);
    scores1_kernel<<<wb1, 256, 0, stream>>>(Wh, aout, ssrc, sdst, N);
    aggout_kernel<<<wb1, 256, 0, stream>>>(Wh, ssrc, sdst, csr, indptr, out, N);
}

// Round 7
// 623.653 us; speedup vs baseline: 4.5042x; 1.1647x over previous
//
#include <hip/hip_runtime.h>
#include <hip/hip_bf16.h>

#define IN_F   256
#define HID    64
#define HEADS  8
#define OUTC   40
#define ALPHA_SLOPE 0.2f
#define F1     (HEADS*HID)   // 512

typedef short bf16x8 __attribute__((ext_vector_type(8)));
typedef float f32x4  __attribute__((ext_vector_type(4)));

// ---------------- CSR build ----------------

__global__ void hist_kernel(const int* __restrict__ col, int* __restrict__ cnt,
                            int E, int N) {
    int k = blockIdx.x * 256 + threadIdx.x;
    int tot = E + N;
    if (k >= tot) return;
    int c = (k < E) ? col[k] : (k - E);
    atomicAdd(&cnt[c], 1);
}

__global__ __launch_bounds__(1024) void scan1_kernel(
    const int* __restrict__ cnt, int* __restrict__ excl,
    int* __restrict__ bsum, int N) {
    __shared__ int wsum[16];
    int tid = threadIdx.x;
    int i = blockIdx.x * 1024 + tid;
    int lane = tid & 63, wid = tid >> 6;
    int v = (i < N) ? cnt[i] : 0;
    int incl = v;
    #pragma unroll
    for (int off = 1; off < 64; off <<= 1) {
        int t = __shfl_up(incl, off);
        if (lane >= off) incl += t;
    }
    if (lane == 63) wsum[wid] = incl;
    __syncthreads();
    if (wid == 0) {
        int w = (lane < 16) ? wsum[lane] : 0;
        #pragma unroll
        for (int off = 1; off < 16; off <<= 1) {
            int t = __shfl_up(w, off);
            if (lane >= off) w += t;
        }
        if (lane < 16) wsum[lane] = w;
    }
    __syncthreads();
    int woff = (wid > 0) ? wsum[wid - 1] : 0;
    int e = woff + incl - v;
    if (i < N) excl[i] = e;
    if (tid == 1023) bsum[blockIdx.x] = woff + incl;
}

__global__ void scan2_kernel(const int* __restrict__ bsum, int* __restrict__ boff,
                             int* __restrict__ indptrN, int nb) {
    int lane = threadIdx.x;
    int v = (lane < nb) ? bsum[lane] : 0;
    int incl = v;
    #pragma unroll
    for (int off = 1; off < 64; off <<= 1) {
        int t = __shfl_up(incl, off);
        if (lane >= off) incl += t;
    }
    if (lane < nb) boff[lane] = incl - v;
    if (lane == 63) *indptrN = incl;
}

__global__ void scan3_kernel(const int* __restrict__ boff, int* __restrict__ indptr,
                             int* __restrict__ fill, int N) {
    int i = blockIdx.x * 256 + threadIdx.x;
    if (i >= N) return;
    int e = indptr[i] + boff[i >> 10];
    indptr[i] = e;
    fill[i] = e;
}

__global__ void scatter_kernel(const int* __restrict__ row, const int* __restrict__ col,
                               int* __restrict__ fill, int* __restrict__ csr,
                               int E, int N) {
    int k = blockIdx.x * 256 + threadIdx.x;
    int tot = E + N;
    if (k >= tot) return;
    int c = (k < E) ? col[k] : (k - E);
    int r = (k < E) ? row[k] : (k - E);
    int pos = atomicAdd(&fill[c], 1);
    csr[pos] = r;
}

// ---------------- prep ----------------

__global__ void cvt_bf16_kernel(const float* __restrict__ in,
                                __hip_bfloat16* __restrict__ out, long n) {
    long i = ((long)blockIdx.x * 256 + threadIdx.x) * 4;
    if (i + 3 >= n) {
        for (long j = i; j < n; j++) out[j] = __float2bfloat16(in[j]);
        return;
    }
    float4 v = *(const float4*)(in + i);
    out[i + 0] = __float2bfloat16(v.x);
    out[i + 1] = __float2bfloat16(v.y);
    out[i + 2] = __float2bfloat16(v.z);
    out[i + 3] = __float2bfloat16(v.w);
}

// W [8][K][64] -> Wt [512][K] bf16
__global__ void prep_w8_kernel(const float* __restrict__ W,
                               __hip_bfloat16* __restrict__ Wt, int K) {
    long i = (long)blockIdx.x * 256 + threadIdx.x;
    long tot = (long)HEADS * K * 64;
    if (i >= tot) return;
    int n = i & 63;
    long rest = i >> 6;
    int k = (int)(rest % K);
    int h = (int)(rest / K);
    Wt[((long)h * 64 + n) * K + k] = __float2bfloat16(W[i]);
}

// Wout [512][40] -> Wt [64][512] bf16, rows 40..63 zero
__global__ void prep_wout_kernel(const float* __restrict__ W,
                                 __hip_bfloat16* __restrict__ Wt) {
    int i = blockIdx.x * 256 + threadIdx.x;
    if (i >= 64 * 512) return;
    int k = i & 511;
    int n = i >> 9;
    Wt[i] = __float2bfloat16(n < OUTC ? W[(long)k * OUTC + n] : 0.f);
}

// ---------------- dense 128x128 bf16 MFMA GEMM + fused scores ----------------
// Each wave's 64x64 tile covers ONE head's full 64 columns -> epilogue computes
// s_src/s_dst for its 64 rows from fp32 accumulators (no separate scores pass).

__global__ __launch_bounds__(256) void gemm128(
    const __hip_bfloat16* __restrict__ A, const __hip_bfloat16* __restrict__ Bt,
    __hip_bfloat16* __restrict__ Cb, const float* __restrict__ av,
    float* __restrict__ ssrc, float* __restrict__ sdst, int M, int K) {
    constexpr int LDA = 40;
    __shared__ __hip_bfloat16 As[128 * LDA];
    __shared__ __hip_bfloat16 Bs[128 * LDA];
    int tid = threadIdx.x;
    int m0 = blockIdx.x * 128;
    int n0 = blockIdx.y * 128;
    int lane = tid & 63, wave = tid >> 6;
    int wm = (wave & 1) * 64, wn = (wave >> 1) * 64;
    int fr = lane & 15, fq = lane >> 4;
    int srow = tid >> 1, scol = (tid & 1) * 16;
    int h = blockIdx.y * 2 + (wave >> 1);     // this wave's head

    const __hip_bfloat16* Arow = A + (long)min(m0 + srow, M - 1) * K;
    const __hip_bfloat16* Brow = Bt + (long)(n0 + srow) * K;

    f32x4 acc[4][4] = {};

    for (int k0 = 0; k0 < K; k0 += 32) {
        float4 av0 = *(const float4*)(Arow + k0 + scol);
        float4 av1 = *(const float4*)(Arow + k0 + scol + 8);
        float4 bv0 = *(const float4*)(Brow + k0 + scol);
        float4 bv1 = *(const float4*)(Brow + k0 + scol + 8);
        __syncthreads();
        *(float4*)(As + srow * LDA + scol) = av0;
        *(float4*)(As + srow * LDA + scol + 8) = av1;
        *(float4*)(Bs + srow * LDA + scol) = bv0;
        *(float4*)(Bs + srow * LDA + scol + 8) = bv1;
        __syncthreads();
        bf16x8 af[4], bfr[4];
        #pragma unroll
        for (int mi = 0; mi < 4; mi++)
            af[mi] = *(const bf16x8*)(As + (wm + mi * 16 + fr) * LDA + fq * 8);
        #pragma unroll
        for (int ni = 0; ni < 4; ni++)
            bfr[ni] = *(const bf16x8*)(Bs + (wn + ni * 16 + fr) * LDA + fq * 8);
        #pragma unroll
        for (int mi = 0; mi < 4; mi++)
            #pragma unroll
            for (int ni = 0; ni < 4; ni++)
                acc[mi][ni] = __builtin_amdgcn_mfma_f32_16x16x32_bf16(
                    af[mi], bfr[ni], acc[mi][ni], 0, 0, 0);
    }

    // C write (bf16)
    #pragma unroll
    for (int mi = 0; mi < 4; mi++)
        #pragma unroll
        for (int ni = 0; ni < 4; ni++)
            #pragma unroll
            for (int rr = 0; rr < 4; rr++) {
                int m = m0 + wm + mi * 16 + fq * 4 + rr;
                int n = n0 + wn + ni * 16 + fr;
                if (m < M)
                    Cb[(long)m * F1 + n] = __float2bfloat16(acc[mi][ni][rr]);
            }

    // fused scores: s = C_tile . a  (per row, this head)
    const float* ah = av + h * 2 * HID;
    float a_src[4], a_dst[4];
    #pragma unroll
    for (int ni = 0; ni < 4; ni++) {
        a_src[ni] = ah[ni * 16 + fr];
        a_dst[ni] = ah[64 + ni * 16 + fr];
    }
    #pragma unroll
    for (int mi = 0; mi < 4; mi++)
        #pragma unroll
        for (int rr = 0; rr < 4; rr++) {
            float ps = 0.f, pd = 0.f;
            #pragma unroll
            for (int ni = 0; ni < 4; ni++) {
                ps += acc[mi][ni][rr] * a_src[ni];
                pd += acc[mi][ni][rr] * a_dst[ni];
            }
            #pragma unroll
            for (int o = 1; o < 16; o <<= 1) {
                ps += __shfl_xor(ps, o);
                pd += __shfl_xor(pd, o);
            }
            int m = m0 + wm + mi * 16 + fq * 4 + rr;
            if (fr == 0 && m < M) {
                ssrc[m * HEADS + h] = ps;
                sdst[m * HEADS + h] = pd;
            }
        }
}

// ---------------- out-layer GEMM (bf16 C [N,40]) + fused scores ----------------

__global__ __launch_bounds__(256) void gemm_out(
    const __hip_bfloat16* __restrict__ A, const __hip_bfloat16* __restrict__ Bt,
    __hip_bfloat16* __restrict__ Cb, const float* __restrict__ av,
    float* __restrict__ ssrc, float* __restrict__ sdst, int M, int K) {
    constexpr int LDA = 40;
    __shared__ __hip_bfloat16 As[128 * LDA];
    __shared__ __hip_bfloat16 Bs[64 * LDA];
    int tid = threadIdx.x;
    int m0 = blockIdx.x * 128;
    int lane = tid & 63, wave = tid >> 6;
    int wm = wave * 32;
    int arow = tid >> 2, acol = (tid & 3) * 8;
    int fr = lane & 15, fq = lane >> 4;

    f32x4 acc[2][4] = {};

    for (int k0 = 0; k0 < K; k0 += 32) {
        int ma = min(m0 + arow, M - 1);
        int mb = min(m0 + 64 + arow, M - 1);
        float4 av1 = *(const float4*)(A + (long)ma * K + k0 + acol);
        float4 av2 = *(const float4*)(A + (long)mb * K + k0 + acol);
        float4 bv  = *(const float4*)(Bt + (long)arow * K + k0 + acol);
        __syncthreads();
        *(float4*)(As + arow * LDA + acol) = av1;
        *(float4*)(As + (64 + arow) * LDA + acol) = av2;
        *(float4*)(Bs + arow * LDA + acol) = bv;
        __syncthreads();
        bf16x8 a0 = *(const bf16x8*)(As + (wm + fr) * LDA + fq * 8);
        bf16x8 a1 = *(const bf16x8*)(As + (wm + 16 + fr) * LDA + fq * 8);
        #pragma unroll
        for (int ni = 0; ni < 4; ni++) {
            bf16x8 b = *(const bf16x8*)(Bs + (ni * 16 + fr) * LDA + fq * 8);
            acc[0][ni] = __builtin_amdgcn_mfma_f32_16x16x32_bf16(a0, b, acc[0][ni], 0, 0, 0);
            acc[1][ni] = __builtin_amdgcn_mfma_f32_16x16x32_bf16(a1, b, acc[1][ni], 0, 0, 0);
        }
    }

    #pragma unroll
    for (int mi = 0; mi < 2; mi++)
        #pragma unroll
        for (int ni = 0; ni < 4; ni++)
            #pragma unroll
            for (int rr = 0; rr < 4; rr++) {
                int m = m0 + wm + mi * 16 + fq * 4 + rr;
                int n = ni * 16 + fr;
                if (m < M && n < OUTC)
                    Cb[(long)m * OUTC + n] = __float2bfloat16(acc[mi][ni][rr]);
            }

    // fused scores over 40 classes
    float a_src[4], a_dst[4];
    #pragma unroll
    for (int ni = 0; ni < 4; ni++) {
        int c = ni * 16 + fr;
        a_src[ni] = (c < OUTC) ? av[c] : 0.f;
        a_dst[ni] = (c < OUTC) ? av[OUTC + c] : 0.f;
    }
    #pragma unroll
    for (int mi = 0; mi < 2; mi++)
        #pragma unroll
        for (int rr = 0; rr < 4; rr++) {
            float ps = 0.f, pd = 0.f;
            #pragma unroll
            for (int ni = 0; ni < 4; ni++) {
                ps += acc[mi][ni][rr] * a_src[ni];
                pd += acc[mi][ni][rr] * a_dst[ni];
            }
            #pragma unroll
            for (int o = 1; o < 16; o <<= 1) {
                ps += __shfl_xor(ps, o);
                pd += __shfl_xor(pd, o);
            }
            int m = m0 + wm + mi * 16 + fq * 4 + rr;
            if (fr == 0 && m < M) {
                ssrc[m] = ps;
                sdst[m] = pd;
            }
        }
}

// ---------------- aggregation: one wave per node, ALL 8 heads ----------------

__global__ __launch_bounds__(256) void agg8_kernel(
    const __hip_bfloat16* __restrict__ Whb, const float* __restrict__ ssrc,
    const float* __restrict__ sdst, const int* __restrict__ csr,
    const int* __restrict__ indptr, __hip_bfloat16* __restrict__ H, int N) {
    int node = blockIdx.x * 4 + (threadIdx.x >> 6);
    if (node >= N) return;
    int lane = threadIdx.x & 63;
    int h = lane >> 3;
    int e8 = lane & 7;
    int base_h = lane & 56;
    int s = __builtin_amdgcn_readfirstlane(indptr[node]);
    int e = __builtin_amdgcn_readfirstlane(indptr[node + 1]);
    float sd = sdst[node * HEADS + h];
    const __hip_bfloat16* wl = Whb + lane * 8;

    float acc[8] = {};
    float m_run = -1e30f, d_run = 0.f;

    for (int jb = s; jb < e; jb += 8) {
        int cnt = min(8, e - jb);
        int src_i = 0;
        float x_i = -1e30f;
        if (e8 < cnt) {
            src_i = csr[jb + e8];
            float x = ssrc[src_i * HEADS + h] + sd;
            x_i = x > 0.f ? x : ALPHA_SLOPE * x;
        }
        float tm = x_i;
        tm = fmaxf(tm, __shfl_xor(tm, 1));
        tm = fmaxf(tm, __shfl_xor(tm, 2));
        tm = fmaxf(tm, __shfl_xor(tm, 4));
        float nm = fmaxf(m_run, tm);
        float scale = __expf(m_run - nm);
        #pragma unroll
        for (int k = 0; k < 8; k++) acc[k] *= scale;
        d_run *= scale;
        m_run = nm;
        float w_i = __expf(x_i - nm);
        float ts = w_i;
        ts += __shfl_xor(ts, 1);
        ts += __shfl_xor(ts, 2);
        ts += __shfl_xor(ts, 4);
        d_run += ts;

        if (cnt == 8) {
            // full tile: issue all 8 gathers before consuming (8 KB in flight/wave)
            uint4 d[8];
            #pragma unroll
            for (int u = 0; u < 8; u++) {
                int su = __shfl(src_i, u);
                d[u] = *(const uint4*)(wl + (long)su * F1);
            }
            #pragma unroll
            for (int u = 0; u < 8; u++) {
                float wj = __shfl(w_i, base_h + u);
                acc[0] += wj * __uint_as_float(d[u].x << 16);
                acc[1] += wj * __uint_as_float(d[u].x & 0xffff0000u);
                acc[2] += wj * __uint_as_float(d[u].y << 16);
                acc[3] += wj * __uint_as_float(d[u].y & 0xffff0000u);
                acc[4] += wj * __uint_as_float(d[u].z << 16);
                acc[5] += wj * __uint_as_float(d[u].z & 0xffff0000u);
                acc[6] += wj * __uint_as_float(d[u].w << 16);
                acc[7] += wj * __uint_as_float(d[u].w & 0xffff0000u);
            }
        } else {
            for (int u = 0; u < cnt; u++) {
                float wj = __shfl(w_i, base_h + u);
                int   su = __shfl(src_i, u);
                uint4 d = *(const uint4*)(wl + (long)su * F1);
                acc[0] += wj * __uint_as_float(d.x << 16);
                acc[1] += wj * __uint_as_float(d.x & 0xffff0000u);
                acc[2] += wj * __uint_as_float(d.y << 16);
                acc[3] += wj * __uint_as_float(d.y & 0xffff0000u);
                acc[4] += wj * __uint_as_float(d.z << 16);
                acc[5] += wj * __uint_as_float(d.z & 0xffff0000u);
                acc[6] += wj * __uint_as_float(d.w << 16);
                acc[7] += wj * __uint_as_float(d.w & 0xffff0000u);
            }
        }
    }

    float inv = 1.f / d_run;
    unsigned short us[8];
    #pragma unroll
    for (int k = 0; k < 8; k++) {
        float v = acc[k] * inv;
        v = v > 0.f ? v : (__expf(v) - 1.f);
        __hip_bfloat16 b = __float2bfloat16(v);
        __builtin_memcpy(&us[k], &b, 2);
    }
    uint4 ov;
    __builtin_memcpy(&ov, us, 16);
    *(uint4*)(H + (long)node * F1 + lane * 8) = ov;
}

// ---------------- out aggregation (bf16 gather) + log_softmax ----------------

__global__ __launch_bounds__(256) void aggout_kernel(
    const __hip_bfloat16* __restrict__ Whb, const float* __restrict__ ssrc,
    const float* __restrict__ sdst, const int* __restrict__ csr,
    const int* __restrict__ indptr, float* __restrict__ out, int N) {
    int node = blockIdx.x * 4 + (threadIdx.x >> 6);
    if (node >= N) return;
    int lane = threadIdx.x & 63;
    int s = __builtin_amdgcn_readfirstlane(indptr[node]);
    int e = __builtin_amdgcn_readfirstlane(indptr[node + 1]);
    float sd = sdst[node];
    int lc = min(lane, OUTC - 1);
    const __hip_bfloat16* whb = Whb + lc;

    float m_run = -1e30f, d_run = 0.f, acc = 0.f;
    for (int t = s; t < e; t += 64) {
        int cnt = min(64, e - t);
        int src_i = node;
        float x_i = -1e30f;
        if (lane < cnt) {
            src_i = csr[t + lane];
            float x = ssrc[src_i] + sd;
            x_i = x > 0.f ? x : ALPHA_SLOPE * x;
        }
        float tm = x_i;
        #pragma unroll
        for (int o = 32; o; o >>= 1) tm = fmaxf(tm, __shfl_xor(tm, o));
        float nm = fmaxf(m_run, tm);
        float scale = __expf(m_run - nm);
        acc *= scale; d_run *= scale;
        m_run = nm;
        float w_i = __expf(x_i - nm);
        float ts = w_i;
        #pragma unroll
        for (int o = 32; o; o >>= 1) ts += __shfl_xor(ts, o);
        d_run += ts;
        int cnt4 = (cnt + 3) & ~3;
        for (int j = 0; j < cnt4; j += 4) {
            #pragma unroll
            for (int u = 0; u < 4; u++) {
                int   sj = __shfl(src_i, j + u);
                float wj = __shfl(w_i,  j + u);
                acc += wj * __bfloat162float(whb[(long)sj * OUTC]);
            }
        }
    }
    float g = acc / d_run;
    float v = g > 0.f ? g : (__expf(g) - 1.f);
    float vm = (lane < OUTC) ? v : -1e30f;
    #pragma unroll
    for (int o = 32; o; o >>= 1) vm = fmaxf(vm, __shfl_xor(vm, o));
    float ex = (lane < OUTC) ? __expf(v - vm) : 0.f;
    #pragma unroll
    for (int o = 32; o; o >>= 1) ex += __shfl_xor(ex, o);
    if (lane < OUTC) out[(long)node * OUTC + lane] = v - vm - logf(ex);
}

// ---------------- launch ----------------

extern "C" void kernel_launch(void* const* d_in, const int* in_sizes, int n_in,
                              void* d_out, int out_size, void* d_ws, size_t ws_size,
                              hipStream_t stream) {
    const float* x    = (const float*)d_in[0];
    const int*   ei   = (const int*)d_in[1];
    const float* W0   = (const float*)d_in[2];
    const float* a0   = (const float*)d_in[3];
    const float* W1   = (const float*)d_in[4];
    const float* a1   = (const float*)d_in[5];
    const float* Wout = (const float*)d_in[6];
    const float* aout = (const float*)d_in[7];
    float* out = (float*)d_out;

    const int N = in_sizes[0] / IN_F;
    const int E = in_sizes[1] / 2;
    const int Etot = E + N;
    const int* erow = ei;
    const int* ecol = ei + E;

    char* p = (char*)d_ws;
    auto carve = [&](size_t bytes) {
        void* r = (void*)p;
        p += (bytes + 255) & ~(size_t)255;
        return r;
    };
    __hip_bfloat16*  Whb  = (__hip_bfloat16*)carve((size_t)N * F1 * 2);
    __hip_bfloat16*  Hb   = (__hip_bfloat16*)carve((size_t)N * F1 * 2);
    __hip_bfloat16*  WhOb = (__hip_bfloat16*)carve((size_t)N * OUTC * 2);
    __hip_bfloat16*  xb   = (__hip_bfloat16*)carve((size_t)N * IN_F * 2);
    __hip_bfloat16*  Wt0  = (__hip_bfloat16*)carve((size_t)F1 * IN_F * 2);
    __hip_bfloat16*  Wt1  = (__hip_bfloat16*)carve((size_t)F1 * F1 * 2);
    __hip_bfloat16*  WtO  = (__hip_bfloat16*)carve((size_t)64 * F1 * 2);
    float*  ssrc   = (float*)carve((size_t)N * HEADS * 4);
    float*  sdst   = (float*)carve((size_t)N * HEADS * 4);
    int*    cnt    = (int*)carve((size_t)N * 4);
    int*    indptr = (int*)carve((size_t)(N + 1) * 4);
    int*    fill   = (int*)carve((size_t)N * 4);
    int*    csr    = (int*)carve((size_t)Etot * 4);
    int*    bsum   = (int*)carve(64 * 4);
    int*    boff   = (int*)carve(64 * 4);

    // CSR build
    hipMemsetAsync(cnt, 0, (size_t)N * 4, stream);
    int eb = (Etot + 255) / 256;
    int nb = (N + 1023) / 1024;   // <=64 required by scan2
    hist_kernel<<<eb, 256, 0, stream>>>(ecol, cnt, E, N);
    scan1_kernel<<<nb, 1024, 0, stream>>>(cnt, indptr, bsum, N);
    scan2_kernel<<<1, 64, 0, stream>>>(bsum, boff, indptr + N, nb);
    scan3_kernel<<<(N + 255) / 256, 256, 0, stream>>>(boff, indptr, fill, N);
    scatter_kernel<<<eb, 256, 0, stream>>>(erow, ecol, fill, csr, E, N);

    // prep bf16 operands
    long nx = (long)N * IN_F;
    cvt_bf16_kernel<<<(int)((nx / 4 + 255) / 256), 256, 0, stream>>>(x, xb, nx);
    prep_w8_kernel<<<(HEADS * IN_F * 64 + 255) / 256, 256, 0, stream>>>(W0, Wt0, IN_F);
    prep_w8_kernel<<<(HEADS * F1 * 64 + 255) / 256, 256, 0, stream>>>(W1, Wt1, F1);
    prep_wout_kernel<<<(64 * 512 + 255) / 256, 256, 0, stream>>>(Wout, WtO);

    int mt128 = (N + 127) / 128;
    int wb1 = (N + 3) / 4;

    // Layer 0
    gemm128<<<dim3(mt128, 4), 256, 0, stream>>>(xb, Wt0, Whb, a0, ssrc, sdst, N, IN_F);
    agg8_kernel<<<wb1, 256, 0, stream>>>(Whb, ssrc, sdst, csr, indptr, Hb, N);

    // Layer 1
    gemm128<<<dim3(mt128, 4), 256, 0, stream>>>(Hb, Wt1, Whb, a1, ssrc, sdst, N, F1);
    agg8_kernel<<<wb1, 256, 0, stream>>>(Whb, ssrc, sdst, csr, indptr, Hb, N);

    // Out layer
    gemm_out<<<dim3(mt128, 1), 256, 0, stream>>>(Hb, WtO, WhOb, aout, ssrc, sdst, N, F1);
    aggout_kernel<<<wb1, 256, 0, stream>>>(WhOb, ssrc, sdst, csr, indptr, out, N);
}